// Round 13
// baseline (468.553 us; speedup 1.0000x reference)
//
#include <hip/hip_runtime.h>

typedef unsigned short u16;
typedef unsigned int u32;

#define NN 8192
#define NE 65536
#define INV160 0.07905694150420949f   // 1/sqrt(160)

__device__ __forceinline__ float BF(u16 u){ return __uint_as_float(((u32)u)<<16); }
// dual-dtype load: f=1 -> f32, f=0 -> bf16
__device__ __forceinline__ float LD(const void* p, u32 i, int f){
  return f ? ((const float*)p)[i] : BF(((const u16*)p)[i]);
}
// dual int load: f64=1 -> int64, else int32
__device__ __forceinline__ int LDI(const void* p, u32 i, int f64){
  return f64 ? (int)((const long long*)p)[i] : ((const int*)p)[i];
}

// ---------------------------------------------------------------- per-buffer dtype detect
__global__ void k_detect(
    const void* b0, const void* b1, const void* b2, const void* b3,
    const void* b4, const void* b5, const void* b6, const void* b7,
    const void* b8, const void* b9, const void* b10, const void* b11,
    const void* b12, const void* b13, const void* b14, const void* b15,
    const void* b16, const void* b17, const void* b18, const void* b19,
    const void* b20, int* flags)
{
  const void* bufs[21] = {b0,b1,b2,b3,b4,b5,b6,b7,b8,b9,b10,
                          b11,b12,b13,b14,b15,b16,b17,b18,b19,b20};
  int i = threadIdx.x;
  if (i >= 21) return;
  const u32* w = (const u32*)bufs[i];
  if (i == 3){
    int allz = 1;
    for (int k=0;k<32;k++) if (w[2*k+1] != 0u) allz = 0;
    flags[3] = allz;             // 1 = int64
  } else {
    int cnt = 0;
    for (int k=0;k<40;k++){
      u32 lo = w[k] & 0xFFFFu;
      u32 e = (lo>>7)&0xFFu;
      if (e>=123u && e<=131u) cnt++;
    }
    flags[i] = (cnt>=20) ? 0 : 1;  // 0=bf16, 1=f32
  }
}

__global__ void k_sentinel(float* __restrict__ out, int n){
  int i = blockIdx.x*256+threadIdx.x;
  if (i<n) out[i] = 12345.0f;
}

// ---------------------------------------------------------------- per-node prep for one head-chunk (4 heads), 8 nodes/block
// qtab/kbtab per node 640 floats, HEAD-MAJOR: [local head][160] = [0..64) scalar d, [64..160) 3*j+c
// dotAA[n][8] (in d_out scratch): q.kA per head
__global__ __launch_bounds__(384) void k_prep8(
    const void* __restrict__ X, const void* __restrict__ Wq_s,
    const void* __restrict__ Wq_v, const void* __restrict__ Wk_s,
    const void* __restrict__ Wk_v, const int* __restrict__ flags,
    int hc0, float* __restrict__ qtab, float* __restrict__ kbtab,
    float* __restrict__ dotAA)
{
  __shared__ float xr[8][160];
  __shared__ float dsum[8][4];   // [node][local head]
  const int fX=flags[0], fqs=flags[4], fqv=flags[5], fks=flags[6], fkv=flags[7];
  const int fall = fqs & fqv & fks & fkv;
  const int t=threadIdx.x; const int n0=blockIdx.x*8;
  for(int u=t;u<1280;u+=384){ int m=u/160,k=u-m*160; xr[m][k]=LD(X,(u32)(n0+m)*160+k,fX); }
  if (t<32) dsum[t>>2][t&3]=0.f;
  __syncthreads();
  if (t<256){
    // scalar outputs: wave = local head lh=t>>6, dim d=t&63; o = hc0*64 + t
    const int lh=t>>6, d=t&63;
    const int o=hc0*64+t;
    float q[8]={}, ka[8]={}, kb[8]={};
    if (fall){
      const float* wqs=(const float*)Wq_s;
      const float* wks=(const float*)Wk_s;
      for(int i=0;i<64;i++){
        float wq=wqs[(u32)i*512+o], wa=wks[(u32)i*512+o], wb=wks[(u32)(64+i)*512+o];
        #pragma unroll
        for(int m=0;m<8;m++){ float s=xr[m][i]; q[m]+=s*wq; ka[m]+=s*wa; kb[m]+=s*wb; }
      }
    } else {
      for(int i=0;i<64;i++){
        float wq=LD(Wq_s,(u32)i*512+o,fqs);
        float wa=LD(Wk_s,(u32)i*512+o,fks);
        float wb=LD(Wk_s,(u32)(64+i)*512+o,fks);
        #pragma unroll
        for(int m=0;m<8;m++){ float s=xr[m][i]; q[m]+=s*wq; ka[m]+=s*wa; kb[m]+=s*wb; }
      }
    }
    #pragma unroll
    for(int m=0;m<8;m++){
      float qs = q[m]*0.125f;                    // 1/sqrt(64)
      float kas= ka[m]*0.08838834764831845f;     // 1/sqrt(128)
      float kbs= kb[m]*0.08838834764831845f;
      u32 base=(u32)(n0+m)*640 + lh*160 + d;
      qtab [base]=qs;
      kbtab[base]=kbs;
      float dd=qs*kas;
      for(int s2=1;s2<64;s2<<=1) dd+=__shfl_xor(dd,s2,64);
      if(d==0) atomicAdd(&dsum[m][lh],dd);
    }
  } else {
    // vector outputs: ol in [0,128), local head lh=ol>>5, j=ol&31; ov = hc0*32 + ol
    const int ol=t-256;
    const int lh=ol>>5, jj=ol&31;
    const int o=hc0*32+ol;
    float q[8][3]={}, ka[8][3]={}, kb[8][3]={};
    if (fall){
      const float* wqv=(const float*)Wq_v;
      const float* wkv=(const float*)Wk_v;
      for(int j=0;j<32;j++){
        float wq=wqv[(u32)j*256+o], wa=wkv[(u32)j*256+o], wb=wkv[(u32)(32+j)*256+o];
        #pragma unroll
        for(int m=0;m<8;m++){
          #pragma unroll
          for(int c=0;c<3;c++){
            float x=xr[m][64+j*3+c];
            q[m][c]+=x*wq; ka[m][c]+=x*wa; kb[m][c]+=x*wb;
          }
        }
      }
    } else {
      for(int j=0;j<32;j++){
        float wq=LD(Wq_v,(u32)j*256+o,fqv);
        float wa=LD(Wk_v,(u32)j*256+o,fkv);
        float wb=LD(Wk_v,(u32)(32+j)*256+o,fkv);
        #pragma unroll
        for(int m=0;m<8;m++){
          #pragma unroll
          for(int c=0;c<3;c++){
            float x=xr[m][64+j*3+c];
            q[m][c]+=x*wq; ka[m][c]+=x*wa; kb[m][c]+=x*wb;
          }
        }
      }
    }
    const float sq=0.17677669529663687f;   // 1/sqrt(32)
    const float sk=0.125f;                 // 1/sqrt(64)
    #pragma unroll
    for(int m=0;m<8;m++){
      float dd=0.f;
      u32 base=(u32)(n0+m)*640 + lh*160 + 64 + (u32)jj*3;
      #pragma unroll
      for(int c=0;c<3;c++){
        float qs=q[m][c]*sq, kas=ka[m][c]*sk, kbs=kb[m][c]*sk;
        qtab[base+c]=qs; kbtab[base+c]=kbs;
        dd+=qs*kas;
      }
      for(int s2=1;s2<32;s2<<=1) dd+=__shfl_xor(dd,s2,64);
      if((t&31)==0) atomicAdd(&dsum[m][lh],dd);
    }
  }
  __syncthreads();
  if (t<32){ int m=t>>2, hh=t&3; dotAA[(u32)(n0+m)*8+hc0+hh]=dsum[m][hh]; }
}

// ---------------------------------------------------------------- per-edge logits for one 4-head chunk
// 8 edges/block via elist, 1 wave/edge; head-major tables: 16 lanes per head,
// 40 contiguous float4 per head, single-accumulator 4-level reduce
__global__ __launch_bounds__(512) void k_elog4(
    const void* __restrict__ ei, const int* __restrict__ flags,
    const float* __restrict__ qtab, const float* __restrict__ kbtab,
    const float* __restrict__ dotAA, const u32* __restrict__ elist,
    int hc0, float* __restrict__ logits)
{
  const int f64=flags[3];
  const int t=threadIdx.x;
  const int e=(int)elist[(u32)blockIdx.x*8+(t>>6)], l=t&63;
  const int src=LDI(ei,(u32)e,f64);
  const int dst=LDI(ei,(u32)NE+e,f64);
  const float4* q4=(const float4*)qtab + (u32)src*160;
  const float4* b4=(const float4*)kbtab + (u32)dst*160;
  const int hg=l>>4, lg=l&15;
  const int base4=hg*40;
  float acc;
  {
    float4 a=q4[base4+lg], b=b4[base4+lg];
    acc=a.x*b.x+a.y*b.y+a.z*b.z+a.w*b.w;
  }
  {
    float4 a=q4[base4+16+lg], b=b4[base4+16+lg];
    acc+=a.x*b.x+a.y*b.y+a.z*b.z+a.w*b.w;
  }
  if (lg<8){
    float4 a=q4[base4+32+lg], b=b4[base4+32+lg];
    acc+=a.x*b.x+a.y*b.y+a.z*b.z+a.w*b.w;
  }
  #pragma unroll
  for(int m=1;m<16;m<<=1) acc+=__shfl_xor(acc,m,64);
  if (lg==0)
    logits[(u32)e*8+hc0+hg]=(dotAA[(u32)src*8+hc0+hg]+acc)*INV160;
}

// ---------------------------------------------------------------- weight folding: (Wv,Wm) -> Wfold, Vfold
__global__ __launch_bounds__(256) void k_fold(
    const void* __restrict__ Wv_s, const void* __restrict__ Wv_v,
    const void* __restrict__ Wm_s, const void* __restrict__ Wm_v,
    const int* __restrict__ flags,
    float* __restrict__ Wfold, float* __restrict__ Vfold)
{
  const int fvs=flags[11], fvv=flags[12], fms=flags[13], fmv=flags[14];
  const int b=blockIdx.x, t=threadIdx.x;
  if (b<128){
    int idx=b*256+t;            // [0,32768)
    int i=idx>>6, o=idx&63;
    int h=i>>6, iin=i&63;
    float a=0.f;
    for(int d=0;d<64;d++)
      a += LD(Wv_s,(u32)iin*512 + h*64 + d, fvs) * LD(Wm_s,(u32)(h*64+d)*64 + o, fms);
    Wfold[idx]=a*0.0055242717280199026f;   // 0.125 * 1/sqrt(512)
  } else {
    int idx=(b-128)*256+t;      // [0,8192)
    int h=idx>>10, r=idx&1023, j2=r>>5, o2=r&31;
    float a=0.f;
    for(int dl=0;dl<32;dl++){
      int i2=h*32+dl;
      a += (LD(Wv_v,(u32)j2*256+i2,fvv)+LD(Wv_v,(u32)(32+j2)*256+i2,fvv))
           *LD(Wm_v,(u32)i2*32+o2,fmv);
    }
    Vfold[idx]=a*0.0078125f;               // 0.125 * 0.0625  (idx = h*1024 + j2*32 + o2)
  }
}

// ---------------------------------------------------------------- per-node pA/pB halves of the p-linear, 4 nodes/block
__global__ __launch_bounds__(256) void k_pprep(
    const void* __restrict__ X, const void* __restrict__ Wp_s,
    const void* __restrict__ Wp_v, const int* __restrict__ flags,
    float* __restrict__ pA, float* __restrict__ pB)
{
  __shared__ float xr[4][160];
  const int fX=flags[0], fps=flags[8], fpv=flags[9];
  const int t=threadIdx.x, n0=blockIdx.x*4;
  for(int u=t;u<640;u+=256){ int m=u/160,k=u-m*160; xr[m][k]=LD(X,(u32)(n0+m)*160+k,fX); }
  __syncthreads();
  if (t<64){
    const int j=t&31, half=t>>5;
    float a[4]={0.f,0.f,0.f,0.f};
    if (fps){
      const float* wp=(const float*)Wp_s;
      for(int i=0;i<64;i++){
        float w=wp[(u32)(half*64+i)*32+j];
        #pragma unroll
        for(int m=0;m<4;m++) a[m]+=xr[m][i]*w;
      }
    } else {
      for(int i=0;i<64;i++){
        float w=LD(Wp_s,(u32)(half*64+i)*32+j,fps);
        #pragma unroll
        for(int m=0;m<4;m++) a[m]+=xr[m][i]*w;
      }
    }
    float* d_ = half? pB:pA;
    #pragma unroll
    for(int m=0;m<4;m++) d_[(u32)(n0+m)*128+j]=a[m]*0.08838834764831845f;  // 1/sqrt(128)
  } else {
    const int idx=t-64;        // [0,192)
    const int half=idx/96;
    const int r=idx-half*96;   // [0,96)
    const int j=r/3, c=r-3*j;
    float a[4]={0.f,0.f,0.f,0.f};
    if (fpv){
      const float* wp=(const float*)Wp_v;
      for(int k=0;k<32;k++){
        float w=wp[(u32)(half*32+k)*32+j];
        #pragma unroll
        for(int m=0;m<4;m++) a[m]+=xr[m][64+k*3+c]*w;
      }
    } else {
      for(int k=0;k<32;k++){
        float w=LD(Wp_v,(u32)(half*32+k)*32+j,fpv);
        #pragma unroll
        for(int m=0;m<4;m++) a[m]+=xr[m][64+k*3+c]*w;
      }
    }
    float* d_ = half? pB:pA;
    #pragma unroll
    for(int m=0;m<4;m++) d_[(u32)(n0+m)*128+32+j*3+c]=a[m]*0.125f;         // 1/sqrt(64)
  }
}

// ---------------------------------------------------------------- CSR build (lives in dead imax/den buffers)
__global__ __launch_bounds__(256) void k_count(
    const void* __restrict__ ei, const int* __restrict__ flags,
    u32* __restrict__ cnt)
{
  int e = blockIdx.x*256 + threadIdx.x;
  int dst = LDI(ei,(u32)NE+e,flags[3]);
  atomicAdd(&cnt[dst],1u);
}
// single block: exclusive scan of 8192 counts -> offsets (+copy for cursor)
__global__ __launch_bounds__(256) void k_scan(
    u32* __restrict__ cnt, u32* __restrict__ off, u32* __restrict__ cur)
{
  __shared__ u32 s[NN];
  __shared__ u32 tsum[256];
  const int t=threadIdx.x;
  for(int u=t;u<NN;u+=256) s[u]=cnt[u];
  __syncthreads();
  const u32 base=(u32)t*32;
  u32 sum=0;
  for(int k=0;k<32;k++) sum+=s[base+k];
  tsum[t]=sum;
  __syncthreads();
  if(t==0){
    u32 run=0;
    for(int i=0;i<256;i++){ u32 v=tsum[i]; tsum[i]=run; run+=v; }
  }
  __syncthreads();
  u32 run=tsum[t];
  for(int k=0;k<32;k++){
    u32 v=s[base+k];
    off[base+k]=run; cur[base+k]=run;
    run+=v;
  }
  if(t==255) off[NN]=run;   // = NE
}
__global__ __launch_bounds__(256) void k_fill(
    const void* __restrict__ ei, const int* __restrict__ flags,
    u32* __restrict__ cur, u32* __restrict__ elist)
{
  int e = blockIdx.x*256 + threadIdx.x;
  int dst = LDI(ei,(u32)NE+e,flags[3]);
  u32 p = atomicAdd(&cur[dst],1u);
  elist[p] = (u32)e;
}

// ---------------------------------------------------------------- per-node: fused softmax + edge-u + gather + folded tail, 4 NODES/BLOCK
// ag stride padded to 1288 (8 mod 32 -> groups on distinct banks); partf padded to 65
__global__ __launch_bounds__(256) void k_nodeval(
    const float* __restrict__ logits, const float* __restrict__ pA,
    const float* __restrict__ pBt,
    const u32* __restrict__ off, const u32* __restrict__ elist,
    const void* __restrict__ ei, const void* __restrict__ rbf,
    const void* __restrict__ rsh, const void* __restrict__ Wrbf,
    const float* __restrict__ Wfold, const float* __restrict__ Vfold,
    const void* __restrict__ ln_g, const void* __restrict__ ln_b,
    const void* __restrict__ W1, const void* __restrict__ b1,
    const void* __restrict__ W2, const void* __restrict__ b2,
    const int* __restrict__ flags, float* __restrict__ out)
{
  __shared__ float ag[4][1288];    // 20.6 KB, persists across phases (pad: 1288%32=8)
  __shared__ float smemf[4096];    // 16 KB overlay region
  __shared__ int   ebuf[8];
  // edge-phase aliases
  float* wrb = smemf;                                  // [1024]
  float (*pB4)[128]  = (float(*)[128])(smemf+1024);    // [4][128]
  float (*ubuf)[160] = (float(*)[160])(smemf+1536);    // [8][160] ends 2816
  // tail-phase aliases (padded partf)
  float (*partf)[4][65] = (float(*)[4][65])smemf;      // [4][4][65] ends 1040
  float (*partv)[192] = (float(*)[192])(smemf+1040);   // ends 1808
  float (*mrow)[160]  = (float(*)[160])(smemf+1808);   // ends 2448
  float (*n0_)[96]    = (float(*)[96])(smemf+2448);    // ends 2832
  float (*x1_)[96]    = (float(*)[96])(smemf+2832);    // ends 3216
  float (*y1_)[96]    = (float(*)[96])(smemf+3216);    // ends 3600
  float (*fl_)[96]    = (float(*)[96])(smemf+3600);    // ends 3984
  float* stat = smemf+3984;                            // mu[4], rstd[4]

  const int frb=flags[1], frs=flags[2], f64=flags[3], fwr=flags[10];
  const int fg=flags[15], fbb=flags[16], f1=flags[17], fb1=flags[18];
  const int f2=flags[19], fb2=flags[20];
  const int fastg = frb & frs;
  const int fastt = f1 & f2;
  const int t=threadIdx.x; const int g4=blockIdx.x*4;
  for(int u=t;u<1024;u+=256) wrb[u]=LD(Wrbf,u,fwr);
  #pragma unroll
  for(int m=0;m<4;m++) if (t<128) pB4[m][t]=pBt[(u32)(g4+m)*128+t];
  __syncthreads();

  const int h=t>>5, j=t&31;

  // -------- edge phase: loop over the block's 4 nodes
  for (int m=0;m<4;m++){
    const int n=g4+m;
    const u32 o0=off[n], o1=off[n+1];
    // fused scatter-softmax stats per (n,h)
    float mx=-3.4e38f;
    for(u32 p=o0+j; p<o1; p+=32) mx=fmaxf(mx, logits[(u32)elist[p]*8+h]);
    #pragma unroll
    for(int s2=1;s2<32;s2<<=1) mx=fmaxf(mx, __shfl_xor(mx,s2,64));
    float sm=0.f;
    for(u32 p=o0+j; p<o1; p+=32) sm+=__expf(logits[(u32)elist[p]*8+h]-mx);
    #pragma unroll
    for(int s2=1;s2<32;s2<<=1) sm+=__shfl_xor(sm,s2,64);
    const float winv=(sm>0.f)?1.f/sm:0.f;

    float a0=0.f,a1=0.f,a2=0.f,a3=0.f,a4=0.f;
    for (u32 base=o0; base<o1; base+=8){
      u32 rem=o1-base; int nb = rem<8u ? (int)rem : 8;
      if (h<nb){
        u32 e=elist[base+h];
        if (j==0) ebuf[h]=(int)e;
        int src=LDI(ei,e,f64);
        const float* pa=pA+(u32)src*128;
        float ps  = pa[j]        + pB4[m][j];
        float pv0 = pa[32+j*3+0] + pB4[m][32+j*3+0];
        float pv1 = pa[32+j*3+1] + pB4[m][32+j*3+1];
        float pv2 = pa[32+j*3+2] + pB4[m][32+j*3+2];
        float scs=0.f, scv=0.f;
        float rs0,rs1,rs2,rs3;
        if (fastg){
          const float* rb=(const float*)rbf + (size_t)e*16;
          #pragma unroll
          for(int r=0;r<16;r++){
            float x=rb[r];
            scs+=x*wrb[r*64+j]; scv+=x*wrb[r*64+32+j];
          }
          const float* rs=(const float*)rsh + (size_t)e*128;
          rs0=rs[j]; rs1=rs[32+j*3+0]; rs2=rs[32+j*3+1]; rs3=rs[32+j*3+2];
        } else {
          for(int r=0;r<16;r++){
            float x=LD(rbf,(u32)e*16+r,frb);
            scs+=x*wrb[r*64+j]; scv+=x*wrb[r*64+32+j];
          }
          rs0=LD(rsh,(u32)e*128+j,frs);
          rs1=LD(rsh,(u32)e*128+32+j*3+0,frs);
          rs2=LD(rsh,(u32)e*128+32+j*3+1,frs);
          rs3=LD(rsh,(u32)e*128+32+j*3+2,frs);
        }
        float ss = rs0 * scs * ps;
        float v0 = rs1 * scv * pv0;
        float v1 = rs2 * scv * pv1;
        float v2 = rs3 * scv * pv2;
        ubuf[h][j]        = ss*ss;
        ubuf[h][32+j]     = (v0*v0+v1*v1+v2*v2)*0.57735026918962576f;
        ubuf[h][64+3*j+0] = ss*v0;
        ubuf[h][64+3*j+1] = ss*v1;
        ubuf[h][64+3*j+2] = ss*v2;
      }
      __syncthreads();
      for(int q=0;q<nb;q++){
        float w=__expf(logits[(u32)ebuf[q]*8+h]-mx)*winv;
        a0+=w*ubuf[q][j];        a1+=w*ubuf[q][32+j];
        a2+=w*ubuf[q][64+3*j+0]; a3+=w*ubuf[q][64+3*j+1]; a4+=w*ubuf[q][64+3*j+2];
      }
      __syncthreads();
    }
    ag[m][h*64+j]=a0; ag[m][h*64+32+j]=a1;
    ag[m][512+h*96+3*j+0]=a2; ag[m][512+h*96+3*j+1]=a3; ag[m][512+h*96+3*j+2]=a4;
  }
  __syncthreads();   // edge-phase LDS dead; tail overlay begins

  // -------- folded scalar path: thread (o4=t&15, pp=t>>4): m=pp&3, i-group gq=pp>>2
  {
    const int o4=t&15, pp=t>>4;
    const int m=pp&3, gq=pp>>2;
    const float4* Wf4=(const float4*)Wfold;
    float ax=0.f,ay=0.f,az=0.f,aw=0.f;
    const int i0=gq*128;
    for(int i=i0;i<i0+128;i++){
      float a=ag[m][i];
      float4 wv=Wf4[(u32)i*16+o4];
      ax+=a*wv.x; ay+=a*wv.y; az+=a*wv.z; aw+=a*wv.w;
    }
    partf[gq][m][o4*4+0]=ax; partf[gq][m][o4*4+1]=ay;
    partf[gq][m][o4*4+2]=az; partf[gq][m][o4*4+3]=aw;
  }
  // folded vector path: loads shared across the 4 nodes
  if (t<192){
    const int o2=t&31, c=(t>>5)%3, p=t/96;
    float a[4]={0.f,0.f,0.f,0.f};
    for(int hh=p*4;hh<p*4+4;hh++)
      for(int j2=0;j2<32;j2++){
        float v=Vfold[(u32)hh*1024+j2*32+o2];
        #pragma unroll
        for(int m=0;m<4;m++) a[m]+=ag[m][512+hh*96+j2*3+c]*v;
      }
    #pragma unroll
    for(int m=0;m<4;m++) partv[m][t]=a[m];
  }
  __syncthreads();
  {
    const int o=t&63, m=t>>6;
    mrow[m][o]=partf[0][m][o]+partf[1][m][o]+partf[2][m][o]+partf[3][m][o];
  }
  if (t<96){
    #pragma unroll
    for(int m=0;m<4;m++)
      mrow[m][64+(t&31)*3+(t>>5)]=partv[m][t]+partv[m][t+96];
  }
  __syncthreads();

  if (t<96){
    #pragma unroll
    for(int m=0;m<4;m++){
      float val;
      if (t<64) val=fabsf(mrow[m][t]);
      else { int o2=t-64;
        float a=mrow[m][64+o2*3],b=mrow[m][64+o2*3+1],c=mrow[m][64+o2*3+2];
        val=sqrtf(a*a+b*b+c*c); }
      n0_[m][t]=val;
    }
  }
  __syncthreads();
  {
    const int m=t>>6;
    float mu=0.f,ss2=0.f;
    for(int i=0;i<96;i++){ float v=n0_[m][i]; mu+=v; ss2+=v*v; }
    mu*=(1.f/96.f);
    float var=fmaxf(ss2*(1.f/96.f)-mu*mu,0.f);
    float rstd=rsqrtf(var+1e-5f);
    if ((t&63)==0){ stat[m]=mu; stat[4+m]=rstd; }
  }
  __syncthreads();
  if (t<96){
    float gv = fg  ? ((const float*)ln_g)[t] : LD(ln_g,t,fg);
    float bv = fbb ? ((const float*)ln_b)[t] : LD(ln_b,t,fbb);
    #pragma unroll
    for(int m=0;m<4;m++)
      x1_[m][t]=(n0_[m][t]-stat[m])*stat[4+m]*gv+bv;
  }
  __syncthreads();
  if (t<96){
    float bb = fb1 ? ((const float*)b1)[t] : LD(b1,t,fb1);
    float a[4]={bb,bb,bb,bb};
    if (fastt){
      const float* w1=(const float*)W1;
      for(int i=0;i<96;i++){
        float w=w1[(u32)i*96+t];          // lane-coalesced over t
        #pragma unroll
        for(int m=0;m<4;m++) a[m]+=x1_[m][i]*w;
      }
    } else {
      for(int i=0;i<96;i++){
        float w=LD(W1,i*96+t,f1);
        #pragma unroll
        for(int m=0;m<4;m++) a[m]+=x1_[m][i]*w;
      }
    }
    #pragma unroll
    for(int m=0;m<4;m++) y1_[m][t]=a[m]/(1.f+__expf(-a[m]));      // silu
  }
  __syncthreads();
  if (t<96){
    float bb = fb2 ? ((const float*)b2)[t] : LD(b2,t,fb2);
    float a[4]={bb,bb,bb,bb};
    if (fastt){
      const float* w2=(const float*)W2;
      for(int i=0;i<96;i++){
        float w=w2[(u32)i*96+t];
        #pragma unroll
        for(int m=0;m<4;m++) a[m]+=y1_[m][i]*w;
      }
    } else {
      for(int i=0;i<96;i++){
        float w=LD(W2,i*96+t,f2);
        #pragma unroll
        for(int m=0;m<4;m++) a[m]+=y1_[m][i]*w;
      }
    }
    #pragma unroll
    for(int m=0;m<4;m++){
      float gg=a[m]/(1.f+__expf(-a[m]));
      fl_[m][t]=gg/(n0_[m][t]+1e-6f);
    }
  }
  __syncthreads();
  if (t<160){
    #pragma unroll
    for(int m=0;m<4;m++){
      float v;
      if (t<64) v=mrow[m][t]*fl_[m][t];
      else { int q=t-64; int o2=q/3; v=mrow[m][t]*fl_[m][64+o2]; }
      out[(u32)(g4+m)*160+t]=v;
    }
  }
}

// ---------------------------------------------------------------- launch
extern "C" void kernel_launch(void* const* d_in, const int* in_sizes, int n_in,
                              void* d_out, int out_size, void* d_ws, size_t ws_size,
                              hipStream_t stream)
{
  (void)in_sizes; (void)n_in;
  const void* X    = d_in[0];
  const void* rbf  = d_in[1];
  const void* rsh  = d_in[2];
  const void* ei   = d_in[3];
  const void* Wq_s = d_in[4];
  const void* Wq_v = d_in[5];
  const void* Wk_s = d_in[6];
  const void* Wk_v = d_in[7];
  const void* Wp_s = d_in[8];
  const void* Wp_v = d_in[9];
  const void* Wrbf = d_in[10];
  const void* Wv_s = d_in[11];
  const void* Wv_v = d_in[12];
  const void* Wm_s = d_in[13];
  const void* Wm_v = d_in[14];
  const void* ln_g = d_in[15];
  const void* ln_b = d_in[16];
  const void* W1   = d_in[17];
  const void* b1   = d_in[18];
  const void* W2   = d_in[19];
  const void* b2   = d_in[20];

  // ws layout (~44.5 MB) — identical footprint to the passing baseline
  char* w = (char*)d_ws;
  int* flags     = (int*)w;   w += 256;
  float* logits  = (float*)w; w += (size_t)NE*8*4;   // raw logits (softmax fused in nodeval)
  u32* imax      = (u32*)w;   w += (size_t)NN*8*4;   // CSR off/cur + Wfold/Vfold
  float* den     = (float*)w; w += (size_t)NN*8*4;   // CSR edge list
  char* uni = w;              w += (size_t)NN*1280*4;
  // uni phase 1: qtab | kbtab (4-head chunk tables, exact fit);
  // phase 2: pA | pB (overlay dead qtab)
  float* qtab  = (float*)uni;
  float* kbtab = (float*)(uni + (size_t)NN*640*4);
  float* pA    = (float*)uni;
  float* pB    = (float*)(uni + (size_t)NN*128*4);
  // imax sub-layout:
  //   [0, 32772)        csr counts -> csr_off (NN+1 u32)
  //   [49152, 81920)    csr_cur (NN u32)
  //   [98304, 229376)   Wfold (512*64 f32 = 128KB)
  //   [229376, 262144)  Vfold (8*32*32 f32 = 32KB)
  u32* csr_off = imax;
  u32* csr_cur = imax + 12288;
  float* Wfold = (float*)((char*)imax + 98304);
  float* Vfold = (float*)((char*)imax + 229376);
  u32* elist   = (u32*)den;            // NE u32 = 256KB exact
  // dotAA[NN][8] scratch lives in d_out (fully overwritten by k_nodeval)
  float* dotAA = (float*)d_out;
  size_t required = (size_t)(w - (char*)d_ws);

  if (ws_size < required){
    k_sentinel<<<(out_size+255)/256,256,0,stream>>>((float*)d_out, out_size);
    return;
  }

  k_detect<<<1,64,0,stream>>>(X,rbf,rsh,ei,Wq_s,Wq_v,Wk_s,Wk_v,Wp_s,Wp_v,
                              Wrbf,Wv_s,Wv_v,Wm_s,Wm_v,ln_g,ln_b,W1,b1,W2,b2,flags);
  // weight folding + CSR build
  k_fold<<<160,256,0,stream>>>(Wv_s,Wv_v,Wm_s,Wm_v,flags,Wfold,Vfold);
  hipMemsetAsync(imax, 0, (size_t)NN*4, stream);                 // counts = 0
  k_count<<<NE/256,256,0,stream>>>(ei,flags,imax);
  k_scan<<<1,256,0,stream>>>(imax,csr_off,csr_cur);
  k_fill<<<NE/256,256,0,stream>>>(ei,flags,csr_cur,elist);
  // 2 head-chunks (4 heads each): 8-node prep (head-major tables) then elist-grouped logits
  for (int c=0;c<2;c++){
    k_prep8<<<NN/8,384,0,stream>>>(X,Wq_s,Wq_v,Wk_s,Wk_v,flags,c*4,qtab,kbtab,dotAA);
    k_elog4<<<NE/8,512,0,stream>>>(ei,flags,qtab,kbtab,dotAA,elist,c*4,logits);
  }
  // phase 2: per-node p-halves (4 nodes/block, overlay dead tables), then fused softmax+gather+tail
  k_pprep<<<NN/4,256,0,stream>>>(X,Wp_s,Wp_v,flags,pA,pB);
  k_nodeval<<<NN/4,256,0,stream>>>(logits,pA,pB,csr_off,elist,ei,rbf,rsh,Wrbf,
                                   Wfold,Vfold,ln_g,ln_b,W1,b1,W2,b2,flags,(float*)d_out);
}

// Round 14
// 420.869 us; speedup vs baseline: 1.1133x; 1.1133x over previous
//
#include <hip/hip_runtime.h>

typedef unsigned short u16;
typedef unsigned int u32;

#define NN 8192
#define NE 65536
#define INV160 0.07905694150420949f   // 1/sqrt(160)

__device__ __forceinline__ float BF(u16 u){ return __uint_as_float(((u32)u)<<16); }
// dual-dtype load: f=1 -> f32, f=0 -> bf16
__device__ __forceinline__ float LD(const void* p, u32 i, int f){
  return f ? ((const float*)p)[i] : BF(((const u16*)p)[i]);
}
// dual int load: f64=1 -> int64, else int32
__device__ __forceinline__ int LDI(const void* p, u32 i, int f64){
  return f64 ? (int)((const long long*)p)[i] : ((const int*)p)[i];
}

// ---------------------------------------------------------------- per-buffer dtype detect
__global__ void k_detect(
    const void* b0, const void* b1, const void* b2, const void* b3,
    const void* b4, const void* b5, const void* b6, const void* b7,
    const void* b8, const void* b9, const void* b10, const void* b11,
    const void* b12, const void* b13, const void* b14, const void* b15,
    const void* b16, const void* b17, const void* b18, const void* b19,
    const void* b20, int* flags)
{
  const void* bufs[21] = {b0,b1,b2,b3,b4,b5,b6,b7,b8,b9,b10,
                          b11,b12,b13,b14,b15,b16,b17,b18,b19,b20};
  int i = threadIdx.x;
  if (i >= 21) return;
  const u32* w = (const u32*)bufs[i];
  if (i == 3){
    int allz = 1;
    for (int k=0;k<32;k++) if (w[2*k+1] != 0u) allz = 0;
    flags[3] = allz;             // 1 = int64
  } else {
    int cnt = 0;
    for (int k=0;k<40;k++){
      u32 lo = w[k] & 0xFFFFu;
      u32 e = (lo>>7)&0xFFu;
      if (e>=123u && e<=131u) cnt++;
    }
    flags[i] = (cnt>=20) ? 0 : 1;  // 0=bf16, 1=f32
  }
}

__global__ void k_sentinel(float* __restrict__ out, int n){
  int i = blockIdx.x*256+threadIdx.x;
  if (i<n) out[i] = 12345.0f;
}

// ---------------------------------------------------------------- per-node prep for one head-chunk (4 heads), 4 nodes/block
// qtab/kbtab per node 640 floats, HEAD-MAJOR: [local head][160] = [0..64) scalar d, [64..160) 3*j+c
// dotAA[n][8] (in d_out scratch): q.kA per head
__global__ __launch_bounds__(384) void k_prep4(
    const void* __restrict__ X, const void* __restrict__ Wq_s,
    const void* __restrict__ Wq_v, const void* __restrict__ Wk_s,
    const void* __restrict__ Wk_v, const int* __restrict__ flags,
    int hc0, float* __restrict__ qtab, float* __restrict__ kbtab,
    float* __restrict__ dotAA)
{
  __shared__ float xr[4][160];
  __shared__ float dsum[4][4];   // [node][local head]
  const int fX=flags[0], fqs=flags[4], fqv=flags[5], fks=flags[6], fkv=flags[7];
  const int fall = fqs & fqv & fks & fkv;
  const int t=threadIdx.x; const int n0=blockIdx.x*4;
  for(int u=t;u<640;u+=384){ int m=u/160,k=u-m*160; xr[m][k]=LD(X,(u32)(n0+m)*160+k,fX); }
  if (t<16) dsum[t>>2][t&3]=0.f;
  __syncthreads();
  if (t<256){
    // scalar outputs: local head lh=t>>6, dim d=t&63; o = hc0*64 + t
    const int lh=t>>6, d=t&63;
    const int o=hc0*64+t;
    float q[4]={0,0,0,0}, ka[4]={0,0,0,0}, kb[4]={0,0,0,0};
    if (fall){
      const float* wqs=(const float*)Wq_s;
      const float* wks=(const float*)Wk_s;
      for(int i=0;i<64;i++){
        float wq=wqs[(u32)i*512+o], wa=wks[(u32)i*512+o], wb=wks[(u32)(64+i)*512+o];
        #pragma unroll
        for(int m=0;m<4;m++){ float s=xr[m][i]; q[m]+=s*wq; ka[m]+=s*wa; kb[m]+=s*wb; }
      }
    } else {
      for(int i=0;i<64;i++){
        float wq=LD(Wq_s,(u32)i*512+o,fqs);
        float wa=LD(Wk_s,(u32)i*512+o,fks);
        float wb=LD(Wk_s,(u32)(64+i)*512+o,fks);
        #pragma unroll
        for(int m=0;m<4;m++){ float s=xr[m][i]; q[m]+=s*wq; ka[m]+=s*wa; kb[m]+=s*wb; }
      }
    }
    #pragma unroll
    for(int m=0;m<4;m++){
      float qs = q[m]*0.125f;                    // 1/sqrt(64)
      float kas= ka[m]*0.08838834764831845f;     // 1/sqrt(128)
      float kbs= kb[m]*0.08838834764831845f;
      u32 base=(u32)(n0+m)*640 + lh*160 + d;     // head-major
      qtab [base]=qs;
      kbtab[base]=kbs;
      float dd=qs*kas;
      for(int s2=1;s2<64;s2<<=1) dd+=__shfl_xor(dd,s2,64);
      if(d==0) atomicAdd(&dsum[m][lh],dd);
    }
  } else {
    // vector outputs: ol in [0,128), local head lh=ol>>5, j=ol&31; ov = hc0*32 + ol
    const int ol=t-256;
    const int lh=ol>>5, jj=ol&31;
    const int o=hc0*32+ol;
    float q[4][3]={}, ka[4][3]={}, kb[4][3]={};
    if (fall){
      const float* wqv=(const float*)Wq_v;
      const float* wkv=(const float*)Wk_v;
      for(int j=0;j<32;j++){
        float wq=wqv[(u32)j*256+o], wa=wkv[(u32)j*256+o], wb=wkv[(u32)(32+j)*256+o];
        #pragma unroll
        for(int m=0;m<4;m++){
          #pragma unroll
          for(int c=0;c<3;c++){
            float x=xr[m][64+j*3+c];
            q[m][c]+=x*wq; ka[m][c]+=x*wa; kb[m][c]+=x*wb;
          }
        }
      }
    } else {
      for(int j=0;j<32;j++){
        float wq=LD(Wq_v,(u32)j*256+o,fqv);
        float wa=LD(Wk_v,(u32)j*256+o,fkv);
        float wb=LD(Wk_v,(u32)(32+j)*256+o,fkv);
        #pragma unroll
        for(int m=0;m<4;m++){
          #pragma unroll
          for(int c=0;c<3;c++){
            float x=xr[m][64+j*3+c];
            q[m][c]+=x*wq; ka[m][c]+=x*wa; kb[m][c]+=x*wb;
          }
        }
      }
    }
    const float sq=0.17677669529663687f;   // 1/sqrt(32)
    const float sk=0.125f;                 // 1/sqrt(64)
    #pragma unroll
    for(int m=0;m<4;m++){
      float dd=0.f;
      u32 base=(u32)(n0+m)*640 + lh*160 + 64 + (u32)jj*3;   // head-major
      #pragma unroll
      for(int c=0;c<3;c++){
        float qs=q[m][c]*sq, kas=ka[m][c]*sk, kbs=kb[m][c]*sk;
        qtab[base+c]=qs; kbtab[base+c]=kbs;
        dd+=qs*kas;
      }
      for(int s2=1;s2<32;s2<<=1) dd+=__shfl_xor(dd,s2,64);
      if((t&31)==0) atomicAdd(&dsum[m][lh],dd);
    }
  }
  __syncthreads();
  if (t<16){ int m=t>>2, hh=t&3; dotAA[(u32)(n0+m)*8+hc0+hh]=dsum[m][hh]; }
}

// ---------------------------------------------------------------- per-edge logits for one 4-head chunk
// 8 edges/block via elist, 1 wave/edge; head-major tables: 16 lanes per head,
// 40 contiguous float4 per head, single-accumulator 4-level reduce
__global__ __launch_bounds__(512) void k_elog4(
    const void* __restrict__ ei, const int* __restrict__ flags,
    const float* __restrict__ qtab, const float* __restrict__ kbtab,
    const float* __restrict__ dotAA, const u32* __restrict__ elist,
    int hc0, float* __restrict__ logits)
{
  const int f64=flags[3];
  const int t=threadIdx.x;
  const int e=(int)elist[(u32)blockIdx.x*8+(t>>6)], l=t&63;
  const int src=LDI(ei,(u32)e,f64);
  const int dst=LDI(ei,(u32)NE+e,f64);
  const float4* q4=(const float4*)qtab + (u32)src*160;
  const float4* b4=(const float4*)kbtab + (u32)dst*160;
  const int hg=l>>4, lg=l&15;
  const int base4=hg*40;
  float acc;
  {
    float4 a=q4[base4+lg], b=b4[base4+lg];
    acc=a.x*b.x+a.y*b.y+a.z*b.z+a.w*b.w;
  }
  {
    float4 a=q4[base4+16+lg], b=b4[base4+16+lg];
    acc+=a.x*b.x+a.y*b.y+a.z*b.z+a.w*b.w;
  }
  if (lg<8){
    float4 a=q4[base4+32+lg], b=b4[base4+32+lg];
    acc+=a.x*b.x+a.y*b.y+a.z*b.z+a.w*b.w;
  }
  #pragma unroll
  for(int m=1;m<16;m<<=1) acc+=__shfl_xor(acc,m,64);
  if (lg==0)
    logits[(u32)e*8+hc0+hg]=(dotAA[(u32)src*8+hc0+hg]+acc)*INV160;
}

// ---------------------------------------------------------------- weight folding: (Wv,Wm) -> Wfold, Vfold
__global__ __launch_bounds__(256) void k_fold(
    const void* __restrict__ Wv_s, const void* __restrict__ Wv_v,
    const void* __restrict__ Wm_s, const void* __restrict__ Wm_v,
    const int* __restrict__ flags,
    float* __restrict__ Wfold, float* __restrict__ Vfold)
{
  const int fvs=flags[11], fvv=flags[12], fms=flags[13], fmv=flags[14];
  const int b=blockIdx.x, t=threadIdx.x;
  if (b<128){
    int idx=b*256+t;            // [0,32768)
    int i=idx>>6, o=idx&63;
    int h=i>>6, iin=i&63;
    float a=0.f;
    for(int d=0;d<64;d++)
      a += LD(Wv_s,(u32)iin*512 + h*64 + d, fvs) * LD(Wm_s,(u32)(h*64+d)*64 + o, fms);
    Wfold[idx]=a*0.0055242717280199026f;   // 0.125 * 1/sqrt(512)
  } else {
    int idx=(b-128)*256+t;      // [0,8192)
    int h=idx>>10, r=idx&1023, j2=r>>5, o2=r&31;
    float a=0.f;
    for(int dl=0;dl<32;dl++){
      int i2=h*32+dl;
      a += (LD(Wv_v,(u32)j2*256+i2,fvv)+LD(Wv_v,(u32)(32+j2)*256+i2,fvv))
           *LD(Wm_v,(u32)i2*32+o2,fmv);
    }
    Vfold[idx]=a*0.0078125f;               // 0.125 * 0.0625  (idx = h*1024 + j2*32 + o2)
  }
}

// ---------------------------------------------------------------- per-node pA/pB halves of the p-linear, 4 nodes/block
__global__ __launch_bounds__(256) void k_pprep(
    const void* __restrict__ X, const void* __restrict__ Wp_s,
    const void* __restrict__ Wp_v, const int* __restrict__ flags,
    float* __restrict__ pA, float* __restrict__ pB)
{
  __shared__ float xr[4][160];
  const int fX=flags[0], fps=flags[8], fpv=flags[9];
  const int t=threadIdx.x, n0=blockIdx.x*4;
  for(int u=t;u<640;u+=256){ int m=u/160,k=u-m*160; xr[m][k]=LD(X,(u32)(n0+m)*160+k,fX); }
  __syncthreads();
  if (t<64){
    const int j=t&31, half=t>>5;
    float a[4]={0.f,0.f,0.f,0.f};
    if (fps){
      const float* wp=(const float*)Wp_s;
      for(int i=0;i<64;i++){
        float w=wp[(u32)(half*64+i)*32+j];
        #pragma unroll
        for(int m=0;m<4;m++) a[m]+=xr[m][i]*w;
      }
    } else {
      for(int i=0;i<64;i++){
        float w=LD(Wp_s,(u32)(half*64+i)*32+j,fps);
        #pragma unroll
        for(int m=0;m<4;m++) a[m]+=xr[m][i]*w;
      }
    }
    float* d_ = half? pB:pA;
    #pragma unroll
    for(int m=0;m<4;m++) d_[(u32)(n0+m)*128+j]=a[m]*0.08838834764831845f;  // 1/sqrt(128)
  } else {
    const int idx=t-64;        // [0,192)
    const int half=idx/96;
    const int r=idx-half*96;   // [0,96)
    const int j=r/3, c=r-3*j;
    float a[4]={0.f,0.f,0.f,0.f};
    if (fpv){
      const float* wp=(const float*)Wp_v;
      for(int k=0;k<32;k++){
        float w=wp[(u32)(half*32+k)*32+j];
        #pragma unroll
        for(int m=0;m<4;m++) a[m]+=xr[m][64+k*3+c]*w;
      }
    } else {
      for(int k=0;k<32;k++){
        float w=LD(Wp_v,(u32)(half*32+k)*32+j,fpv);
        #pragma unroll
        for(int m=0;m<4;m++) a[m]+=xr[m][64+k*3+c]*w;
      }
    }
    float* d_ = half? pB:pA;
    #pragma unroll
    for(int m=0;m<4;m++) d_[(u32)(n0+m)*128+32+j*3+c]=a[m]*0.125f;         // 1/sqrt(64)
  }
}

// ---------------------------------------------------------------- CSR build (lives in dead imax/den buffers)
__global__ __launch_bounds__(256) void k_count(
    const void* __restrict__ ei, const int* __restrict__ flags,
    u32* __restrict__ cnt)
{
  int e = blockIdx.x*256 + threadIdx.x;
  int dst = LDI(ei,(u32)NE+e,flags[3]);
  atomicAdd(&cnt[dst],1u);
}
// single block: exclusive scan of 8192 counts -> offsets (+copy for cursor)
__global__ __launch_bounds__(256) void k_scan(
    u32* __restrict__ cnt, u32* __restrict__ off, u32* __restrict__ cur)
{
  __shared__ u32 s[NN];
  __shared__ u32 tsum[256];
  const int t=threadIdx.x;
  for(int u=t;u<NN;u+=256) s[u]=cnt[u];
  __syncthreads();
  const u32 base=(u32)t*32;
  u32 sum=0;
  for(int k=0;k<32;k++) sum+=s[base+k];
  tsum[t]=sum;
  __syncthreads();
  if(t==0){
    u32 run=0;
    for(int i=0;i<256;i++){ u32 v=tsum[i]; tsum[i]=run; run+=v; }
  }
  __syncthreads();
  u32 run=tsum[t];
  for(int k=0;k<32;k++){
    u32 v=s[base+k];
    off[base+k]=run; cur[base+k]=run;
    run+=v;
  }
  if(t==255) off[NN]=run;   // = NE
}
__global__ __launch_bounds__(256) void k_fill(
    const void* __restrict__ ei, const int* __restrict__ flags,
    u32* __restrict__ cur, u32* __restrict__ elist)
{
  int e = blockIdx.x*256 + threadIdx.x;
  int dst = LDI(ei,(u32)NE+e,flags[3]);
  u32 p = atomicAdd(&cur[dst],1u);
  elist[p] = (u32)e;
}

// ---------------------------------------------------------------- per-node: fused softmax + edge-u + gather + folded tail, 4 NODES/BLOCK
// ag stride padded to 1288 (8 mod 32 -> groups on distinct banks); partf padded to 65
__global__ __launch_bounds__(256) void k_nodeval(
    const float* __restrict__ logits, const float* __restrict__ pA,
    const float* __restrict__ pBt,
    const u32* __restrict__ off, const u32* __restrict__ elist,
    const void* __restrict__ ei, const void* __restrict__ rbf,
    const void* __restrict__ rsh, const void* __restrict__ Wrbf,
    const float* __restrict__ Wfold, const float* __restrict__ Vfold,
    const void* __restrict__ ln_g, const void* __restrict__ ln_b,
    const void* __restrict__ W1, const void* __restrict__ b1,
    const void* __restrict__ W2, const void* __restrict__ b2,
    const int* __restrict__ flags, float* __restrict__ out)
{
  __shared__ float ag[4][1288];    // 20.6 KB, persists across phases (pad: 1288%32=8)
  __shared__ float smemf[4096];    // 16 KB overlay region
  __shared__ int   ebuf[8];
  // edge-phase aliases
  float* wrb = smemf;                                  // [1024]
  float (*pB4)[128]  = (float(*)[128])(smemf+1024);    // [4][128]
  float (*ubuf)[160] = (float(*)[160])(smemf+1536);    // [8][160] ends 2816
  // tail-phase aliases (padded partf)
  float (*partf)[4][65] = (float(*)[4][65])smemf;      // [4][4][65] ends 1040
  float (*partv)[192] = (float(*)[192])(smemf+1040);   // ends 1808
  float (*mrow)[160]  = (float(*)[160])(smemf+1808);   // ends 2448
  float (*n0_)[96]    = (float(*)[96])(smemf+2448);    // ends 2832
  float (*x1_)[96]    = (float(*)[96])(smemf+2832);    // ends 3216
  float (*y1_)[96]    = (float(*)[96])(smemf+3216);    // ends 3600
  float (*fl_)[96]    = (float(*)[96])(smemf+3600);    // ends 3984
  float* stat = smemf+3984;                            // mu[4], rstd[4]

  const int frb=flags[1], frs=flags[2], f64=flags[3], fwr=flags[10];
  const int fg=flags[15], fbb=flags[16], f1=flags[17], fb1=flags[18];
  const int f2=flags[19], fb2=flags[20];
  const int fastg = frb & frs;
  const int fastt = f1 & f2;
  const int t=threadIdx.x; const int g4=blockIdx.x*4;
  for(int u=t;u<1024;u+=256) wrb[u]=LD(Wrbf,u,fwr);
  #pragma unroll
  for(int m=0;m<4;m++) if (t<128) pB4[m][t]=pBt[(u32)(g4+m)*128+t];
  __syncthreads();

  const int h=t>>5, j=t&31;

  // -------- edge phase: loop over the block's 4 nodes
  for (int m=0;m<4;m++){
    const int n=g4+m;
    const u32 o0=off[n], o1=off[n+1];
    // fused scatter-softmax stats per (n,h)
    float mx=-3.4e38f;
    for(u32 p=o0+j; p<o1; p+=32) mx=fmaxf(mx, logits[(u32)elist[p]*8+h]);
    #pragma unroll
    for(int s2=1;s2<32;s2<<=1) mx=fmaxf(mx, __shfl_xor(mx,s2,64));
    float sm=0.f;
    for(u32 p=o0+j; p<o1; p+=32) sm+=__expf(logits[(u32)elist[p]*8+h]-mx);
    #pragma unroll
    for(int s2=1;s2<32;s2<<=1) sm+=__shfl_xor(sm,s2,64);
    const float winv=(sm>0.f)?1.f/sm:0.f;

    float a0=0.f,a1=0.f,a2=0.f,a3=0.f,a4=0.f;
    for (u32 base=o0; base<o1; base+=8){
      u32 rem=o1-base; int nb = rem<8u ? (int)rem : 8;
      if (h<nb){
        u32 e=elist[base+h];
        if (j==0) ebuf[h]=(int)e;
        int src=LDI(ei,e,f64);
        const float* pa=pA+(u32)src*128;
        float ps  = pa[j]        + pB4[m][j];
        float pv0 = pa[32+j*3+0] + pB4[m][32+j*3+0];
        float pv1 = pa[32+j*3+1] + pB4[m][32+j*3+1];
        float pv2 = pa[32+j*3+2] + pB4[m][32+j*3+2];
        float scs=0.f, scv=0.f;
        float rs0,rs1,rs2,rs3;
        if (fastg){
          const float* rb=(const float*)rbf + (size_t)e*16;
          #pragma unroll
          for(int r=0;r<16;r++){
            float x=rb[r];
            scs+=x*wrb[r*64+j]; scv+=x*wrb[r*64+32+j];
          }
          const float* rs=(const float*)rsh + (size_t)e*128;
          rs0=rs[j]; rs1=rs[32+j*3+0]; rs2=rs[32+j*3+1]; rs3=rs[32+j*3+2];
        } else {
          for(int r=0;r<16;r++){
            float x=LD(rbf,(u32)e*16+r,frb);
            scs+=x*wrb[r*64+j]; scv+=x*wrb[r*64+32+j];
          }
          rs0=LD(rsh,(u32)e*128+j,frs);
          rs1=LD(rsh,(u32)e*128+32+j*3+0,frs);
          rs2=LD(rsh,(u32)e*128+32+j*3+1,frs);
          rs3=LD(rsh,(u32)e*128+32+j*3+2,frs);
        }
        float ss = rs0 * scs * ps;
        float v0 = rs1 * scv * pv0;
        float v1 = rs2 * scv * pv1;
        float v2 = rs3 * scv * pv2;
        ubuf[h][j]        = ss*ss;
        ubuf[h][32+j]     = (v0*v0+v1*v1+v2*v2)*0.57735026918962576f;
        ubuf[h][64+3*j+0] = ss*v0;
        ubuf[h][64+3*j+1] = ss*v1;
        ubuf[h][64+3*j+2] = ss*v2;
      }
      __syncthreads();
      for(int q=0;q<nb;q++){
        float w=__expf(logits[(u32)ebuf[q]*8+h]-mx)*winv;
        a0+=w*ubuf[q][j];        a1+=w*ubuf[q][32+j];
        a2+=w*ubuf[q][64+3*j+0]; a3+=w*ubuf[q][64+3*j+1]; a4+=w*ubuf[q][64+3*j+2];
      }
      __syncthreads();
    }
    ag[m][h*64+j]=a0; ag[m][h*64+32+j]=a1;
    ag[m][512+h*96+3*j+0]=a2; ag[m][512+h*96+3*j+1]=a3; ag[m][512+h*96+3*j+2]=a4;
  }
  __syncthreads();   // edge-phase LDS dead; tail overlay begins

  // -------- folded scalar path: thread (o4=t&15, pp=t>>4): m=pp&3, i-group gq=pp>>2
  {
    const int o4=t&15, pp=t>>4;
    const int m=pp&3, gq=pp>>2;
    const float4* Wf4=(const float4*)Wfold;
    float ax=0.f,ay=0.f,az=0.f,aw=0.f;
    const int i0=gq*128;
    for(int i=i0;i<i0+128;i++){
      float a=ag[m][i];
      float4 wv=Wf4[(u32)i*16+o4];
      ax+=a*wv.x; ay+=a*wv.y; az+=a*wv.z; aw+=a*wv.w;
    }
    partf[gq][m][o4*4+0]=ax; partf[gq][m][o4*4+1]=ay;
    partf[gq][m][o4*4+2]=az; partf[gq][m][o4*4+3]=aw;
  }
  // folded vector path: loads shared across the 4 nodes
  if (t<192){
    const int o2=t&31, c=(t>>5)%3, p=t/96;
    float a[4]={0.f,0.f,0.f,0.f};
    for(int hh=p*4;hh<p*4+4;hh++)
      for(int j2=0;j2<32;j2++){
        float v=Vfold[(u32)hh*1024+j2*32+o2];
        #pragma unroll
        for(int m=0;m<4;m++) a[m]+=ag[m][512+hh*96+j2*3+c]*v;
      }
    #pragma unroll
    for(int m=0;m<4;m++) partv[m][t]=a[m];
  }
  __syncthreads();
  {
    const int o=t&63, m=t>>6;
    mrow[m][o]=partf[0][m][o]+partf[1][m][o]+partf[2][m][o]+partf[3][m][o];
  }
  if (t<96){
    #pragma unroll
    for(int m=0;m<4;m++)
      mrow[m][64+(t&31)*3+(t>>5)]=partv[m][t]+partv[m][t+96];
  }
  __syncthreads();

  if (t<96){
    #pragma unroll
    for(int m=0;m<4;m++){
      float val;
      if (t<64) val=fabsf(mrow[m][t]);
      else { int o2=t-64;
        float a=mrow[m][64+o2*3],b=mrow[m][64+o2*3+1],c=mrow[m][64+o2*3+2];
        val=sqrtf(a*a+b*b+c*c); }
      n0_[m][t]=val;
    }
  }
  __syncthreads();
  {
    const int m=t>>6;
    float mu=0.f,ss2=0.f;
    for(int i=0;i<96;i++){ float v=n0_[m][i]; mu+=v; ss2+=v*v; }
    mu*=(1.f/96.f);
    float var=fmaxf(ss2*(1.f/96.f)-mu*mu,0.f);
    float rstd=rsqrtf(var+1e-5f);
    if ((t&63)==0){ stat[m]=mu; stat[4+m]=rstd; }
  }
  __syncthreads();
  if (t<96){
    float gv = fg  ? ((const float*)ln_g)[t] : LD(ln_g,t,fg);
    float bv = fbb ? ((const float*)ln_b)[t] : LD(ln_b,t,fbb);
    #pragma unroll
    for(int m=0;m<4;m++)
      x1_[m][t]=(n0_[m][t]-stat[m])*stat[4+m]*gv+bv;
  }
  __syncthreads();
  if (t<96){
    float bb = fb1 ? ((const float*)b1)[t] : LD(b1,t,fb1);
    float a[4]={bb,bb,bb,bb};
    if (fastt){
      const float* w1=(const float*)W1;
      for(int i=0;i<96;i++){
        float w=w1[(u32)i*96+t];          // lane-coalesced over t
        #pragma unroll
        for(int m=0;m<4;m++) a[m]+=x1_[m][i]*w;
      }
    } else {
      for(int i=0;i<96;i++){
        float w=LD(W1,i*96+t,f1);
        #pragma unroll
        for(int m=0;m<4;m++) a[m]+=x1_[m][i]*w;
      }
    }
    #pragma unroll
    for(int m=0;m<4;m++) y1_[m][t]=a[m]/(1.f+__expf(-a[m]));      // silu
  }
  __syncthreads();
  if (t<96){
    float bb = fb2 ? ((const float*)b2)[t] : LD(b2,t,fb2);
    float a[4]={bb,bb,bb,bb};
    if (fastt){
      const float* w2=(const float*)W2;
      for(int i=0;i<96;i++){
        float w=w2[(u32)i*96+t];
        #pragma unroll
        for(int m=0;m<4;m++) a[m]+=y1_[m][i]*w;
      }
    } else {
      for(int i=0;i<96;i++){
        float w=LD(W2,i*96+t,f2);
        #pragma unroll
        for(int m=0;m<4;m++) a[m]+=y1_[m][i]*w;
      }
    }
    #pragma unroll
    for(int m=0;m<4;m++){
      float gg=a[m]/(1.f+__expf(-a[m]));
      fl_[m][t]=gg/(n0_[m][t]+1e-6f);
    }
  }
  __syncthreads();
  if (t<160){
    #pragma unroll
    for(int m=0;m<4;m++){
      float v;
      if (t<64) v=mrow[m][t]*fl_[m][t];
      else { int q=t-64; int o2=q/3; v=mrow[m][t]*fl_[m][64+o2]; }
      out[(u32)(g4+m)*160+t]=v;
    }
  }
}

// ---------------------------------------------------------------- launch
extern "C" void kernel_launch(void* const* d_in, const int* in_sizes, int n_in,
                              void* d_out, int out_size, void* d_ws, size_t ws_size,
                              hipStream_t stream)
{
  (void)in_sizes; (void)n_in;
  const void* X    = d_in[0];
  const void* rbf  = d_in[1];
  const void* rsh  = d_in[2];
  const void* ei   = d_in[3];
  const void* Wq_s = d_in[4];
  const void* Wq_v = d_in[5];
  const void* Wk_s = d_in[6];
  const void* Wk_v = d_in[7];
  const void* Wp_s = d_in[8];
  const void* Wp_v = d_in[9];
  const void* Wrbf = d_in[10];
  const void* Wv_s = d_in[11];
  const void* Wv_v = d_in[12];
  const void* Wm_s = d_in[13];
  const void* Wm_v = d_in[14];
  const void* ln_g = d_in[15];
  const void* ln_b = d_in[16];
  const void* W1   = d_in[17];
  const void* b1   = d_in[18];
  const void* W2   = d_in[19];
  const void* b2   = d_in[20];

  // ws layout (~44.5 MB) — identical footprint to the passing baseline
  char* w = (char*)d_ws;
  int* flags     = (int*)w;   w += 256;
  float* logits  = (float*)w; w += (size_t)NE*8*4;   // raw logits (softmax fused in nodeval)
  u32* imax      = (u32*)w;   w += (size_t)NN*8*4;   // CSR off/cur + Wfold/Vfold
  float* den     = (float*)w; w += (size_t)NN*8*4;   // CSR edge list
  char* uni = w;              w += (size_t)NN*1280*4;
  // uni phase 1: qtab | kbtab (4-head chunk tables, exact fit);
  // phase 2: pA | pB (overlay dead qtab)
  float* qtab  = (float*)uni;
  float* kbtab = (float*)(uni + (size_t)NN*640*4);
  float* pA    = (float*)uni;
  float* pB    = (float*)(uni + (size_t)NN*128*4);
  // imax sub-layout:
  //   [0, 32772)        csr counts -> csr_off (NN+1 u32)
  //   [49152, 81920)    csr_cur (NN u32)
  //   [98304, 229376)   Wfold (512*64 f32 = 128KB)
  //   [229376, 262144)  Vfold (8*32*32 f32 = 32KB)
  u32* csr_off = imax;
  u32* csr_cur = imax + 12288;
  float* Wfold = (float*)((char*)imax + 98304);
  float* Vfold = (float*)((char*)imax + 229376);
  u32* elist   = (u32*)den;            // NE u32 = 256KB exact
  // dotAA[NN][8] scratch lives in d_out (fully overwritten by k_nodeval)
  float* dotAA = (float*)d_out;
  size_t required = (size_t)(w - (char*)d_ws);

  if (ws_size < required){
    k_sentinel<<<(out_size+255)/256,256,0,stream>>>((float*)d_out, out_size);
    return;
  }

  k_detect<<<1,64,0,stream>>>(X,rbf,rsh,ei,Wq_s,Wq_v,Wk_s,Wk_v,Wp_s,Wp_v,
                              Wrbf,Wv_s,Wv_v,Wm_s,Wm_v,ln_g,ln_b,W1,b1,W2,b2,flags);
  // weight folding + CSR build
  k_fold<<<160,256,0,stream>>>(Wv_s,Wv_v,Wm_s,Wm_v,flags,Wfold,Vfold);
  hipMemsetAsync(imax, 0, (size_t)NN*4, stream);                 // counts = 0
  k_count<<<NE/256,256,0,stream>>>(ei,flags,imax);
  k_scan<<<1,256,0,stream>>>(imax,csr_off,csr_cur);
  k_fill<<<NE/256,256,0,stream>>>(ei,flags,csr_cur,elist);
  // 2 head-chunks (4 heads each): 4-node prep (head-major tables) then elist-grouped logits
  for (int c=0;c<2;c++){
    k_prep4<<<NN/4,384,0,stream>>>(X,Wq_s,Wq_v,Wk_s,Wk_v,flags,c*4,qtab,kbtab,dotAA);
    k_elog4<<<NE/8,512,0,stream>>>(ei,flags,qtab,kbtab,dotAA,elist,c*4,logits);
  }
  // phase 2: per-node p-halves (4 nodes/block, overlay dead tables), then fused softmax+gather+tail
  k_pprep<<<NN/4,256,0,stream>>>(X,Wp_s,Wp_v,flags,pA,pB);
  k_nodeval<<<NN/4,256,0,stream>>>(logits,pA,pB,csr_off,elist,ei,rbf,rsh,Wrbf,
                                   Wfold,Vfold,ln_g,ln_b,W1,b1,W2,b2,flags,(float*)d_out);
}

// Round 15
// 407.469 us; speedup vs baseline: 1.1499x; 1.0329x over previous
//
#include <hip/hip_runtime.h>

typedef unsigned short u16;
typedef unsigned int u32;

#define NN 8192
#define NE 65536
#define INV160 0.07905694150420949f   // 1/sqrt(160)

__device__ __forceinline__ float BF(u16 u){ return __uint_as_float(((u32)u)<<16); }
// dual-dtype load: f=1 -> f32, f=0 -> bf16
__device__ __forceinline__ float LD(const void* p, u32 i, int f){
  return f ? ((const float*)p)[i] : BF(((const u16*)p)[i]);
}
// dual int load: f64=1 -> int64, else int32
__device__ __forceinline__ int LDI(const void* p, u32 i, int f64){
  return f64 ? (int)((const long long*)p)[i] : ((const int*)p)[i];
}

// ---------------------------------------------------------------- per-buffer dtype detect
__global__ void k_detect(
    const void* b0, const void* b1, const void* b2, const void* b3,
    const void* b4, const void* b5, const void* b6, const void* b7,
    const void* b8, const void* b9, const void* b10, const void* b11,
    const void* b12, const void* b13, const void* b14, const void* b15,
    const void* b16, const void* b17, const void* b18, const void* b19,
    const void* b20, int* flags)
{
  const void* bufs[21] = {b0,b1,b2,b3,b4,b5,b6,b7,b8,b9,b10,
                          b11,b12,b13,b14,b15,b16,b17,b18,b19,b20};
  int i = threadIdx.x;
  if (i >= 21) return;
  const u32* w = (const u32*)bufs[i];
  if (i == 3){
    int allz = 1;
    for (int k=0;k<32;k++) if (w[2*k+1] != 0u) allz = 0;
    flags[3] = allz;             // 1 = int64
  } else {
    int cnt = 0;
    for (int k=0;k<40;k++){
      u32 lo = w[k] & 0xFFFFu;
      u32 e = (lo>>7)&0xFFu;
      if (e>=123u && e<=131u) cnt++;
    }
    flags[i] = (cnt>=20) ? 0 : 1;  // 0=bf16, 1=f32
  }
}

__global__ void k_sentinel(float* __restrict__ out, int n){
  int i = blockIdx.x*256+threadIdx.x;
  if (i<n) out[i] = 12345.0f;
}

// ---------------------------------------------------------------- per-node prep for one head-chunk (4 heads), 4 nodes/block
// qtab/kbtab per node 640 floats, HEAD-MAJOR: [local head][160] = [0..64) scalar d, [64..160) 3*j+c
// dotAA[n][8] (in d_out scratch): q.kA per head
__global__ __launch_bounds__(384) void k_prep4(
    const void* __restrict__ X, const void* __restrict__ Wq_s,
    const void* __restrict__ Wq_v, const void* __restrict__ Wk_s,
    const void* __restrict__ Wk_v, const int* __restrict__ flags,
    int hc0, float* __restrict__ qtab, float* __restrict__ kbtab,
    float* __restrict__ dotAA)
{
  __shared__ float xr[4][160];
  __shared__ float dsum[4][4];   // [node][local head]
  const int fX=flags[0], fqs=flags[4], fqv=flags[5], fks=flags[6], fkv=flags[7];
  const int fall = fqs & fqv & fks & fkv;
  const int t=threadIdx.x; const int n0=blockIdx.x*4;
  for(int u=t;u<640;u+=384){ int m=u/160,k=u-m*160; xr[m][k]=LD(X,(u32)(n0+m)*160+k,fX); }
  if (t<16) dsum[t>>2][t&3]=0.f;
  __syncthreads();
  if (t<256){
    // scalar outputs: local head lh=t>>6, dim d=t&63; o = hc0*64 + t
    const int lh=t>>6, d=t&63;
    const int o=hc0*64+t;
    float q[4]={0,0,0,0}, ka[4]={0,0,0,0}, kb[4]={0,0,0,0};
    if (fall){
      const float* wqs=(const float*)Wq_s;
      const float* wks=(const float*)Wk_s;
      for(int i=0;i<64;i++){
        float wq=wqs[(u32)i*512+o], wa=wks[(u32)i*512+o], wb=wks[(u32)(64+i)*512+o];
        #pragma unroll
        for(int m=0;m<4;m++){ float s=xr[m][i]; q[m]+=s*wq; ka[m]+=s*wa; kb[m]+=s*wb; }
      }
    } else {
      for(int i=0;i<64;i++){
        float wq=LD(Wq_s,(u32)i*512+o,fqs);
        float wa=LD(Wk_s,(u32)i*512+o,fks);
        float wb=LD(Wk_s,(u32)(64+i)*512+o,fks);
        #pragma unroll
        for(int m=0;m<4;m++){ float s=xr[m][i]; q[m]+=s*wq; ka[m]+=s*wa; kb[m]+=s*wb; }
      }
    }
    #pragma unroll
    for(int m=0;m<4;m++){
      float qs = q[m]*0.125f;                    // 1/sqrt(64)
      float kas= ka[m]*0.08838834764831845f;     // 1/sqrt(128)
      float kbs= kb[m]*0.08838834764831845f;
      u32 base=(u32)(n0+m)*640 + lh*160 + d;     // head-major
      qtab [base]=qs;
      kbtab[base]=kbs;
      float dd=qs*kas;
      for(int s2=1;s2<64;s2<<=1) dd+=__shfl_xor(dd,s2,64);
      if(d==0) atomicAdd(&dsum[m][lh],dd);
    }
  } else {
    // vector outputs: ol in [0,128), local head lh=ol>>5, j=ol&31; ov = hc0*32 + ol
    const int ol=t-256;
    const int lh=ol>>5, jj=ol&31;
    const int o=hc0*32+ol;
    float q[4][3]={}, ka[4][3]={}, kb[4][3]={};
    if (fall){
      const float* wqv=(const float*)Wq_v;
      const float* wkv=(const float*)Wk_v;
      for(int j=0;j<32;j++){
        float wq=wqv[(u32)j*256+o], wa=wkv[(u32)j*256+o], wb=wkv[(u32)(32+j)*256+o];
        #pragma unroll
        for(int m=0;m<4;m++){
          #pragma unroll
          for(int c=0;c<3;c++){
            float x=xr[m][64+j*3+c];
            q[m][c]+=x*wq; ka[m][c]+=x*wa; kb[m][c]+=x*wb;
          }
        }
      }
    } else {
      for(int j=0;j<32;j++){
        float wq=LD(Wq_v,(u32)j*256+o,fqv);
        float wa=LD(Wk_v,(u32)j*256+o,fkv);
        float wb=LD(Wk_v,(u32)(32+j)*256+o,fkv);
        #pragma unroll
        for(int m=0;m<4;m++){
          #pragma unroll
          for(int c=0;c<3;c++){
            float x=xr[m][64+j*3+c];
            q[m][c]+=x*wq; ka[m][c]+=x*wa; kb[m][c]+=x*wb;
          }
        }
      }
    }
    const float sq=0.17677669529663687f;   // 1/sqrt(32)
    const float sk=0.125f;                 // 1/sqrt(64)
    #pragma unroll
    for(int m=0;m<4;m++){
      float dd=0.f;
      u32 base=(u32)(n0+m)*640 + lh*160 + 64 + (u32)jj*3;   // head-major
      #pragma unroll
      for(int c=0;c<3;c++){
        float qs=q[m][c]*sq, kas=ka[m][c]*sk, kbs=kb[m][c]*sk;
        qtab[base+c]=qs; kbtab[base+c]=kbs;
        dd+=qs*kas;
      }
      for(int s2=1;s2<32;s2<<=1) dd+=__shfl_xor(dd,s2,64);
      if((t&31)==0) atomicAdd(&dsum[m][lh],dd);
    }
  }
  __syncthreads();
  if (t<16){ int m=t>>2, hh=t&3; dotAA[(u32)(n0+m)*8+hc0+hh]=dsum[m][hh]; }
}

// ---------------------------------------------------------------- per-edge logits for one 4-head chunk
// 8 edges/block via elist, 1 wave/edge; head-major tables: 16 lanes per head,
// 40 contiguous float4 per head, single-accumulator 4-level reduce
__global__ __launch_bounds__(512) void k_elog4(
    const void* __restrict__ ei, const int* __restrict__ flags,
    const float* __restrict__ qtab, const float* __restrict__ kbtab,
    const float* __restrict__ dotAA, const u32* __restrict__ elist,
    int hc0, float* __restrict__ logits)
{
  const int f64=flags[3];
  const int t=threadIdx.x;
  const int e=(int)elist[(u32)blockIdx.x*8+(t>>6)], l=t&63;
  const int src=LDI(ei,(u32)e,f64);
  const int dst=LDI(ei,(u32)NE+e,f64);
  const float4* q4=(const float4*)qtab + (u32)src*160;
  const float4* b4=(const float4*)kbtab + (u32)dst*160;
  const int hg=l>>4, lg=l&15;
  const int base4=hg*40;
  float acc;
  {
    float4 a=q4[base4+lg], b=b4[base4+lg];
    acc=a.x*b.x+a.y*b.y+a.z*b.z+a.w*b.w;
  }
  {
    float4 a=q4[base4+16+lg], b=b4[base4+16+lg];
    acc+=a.x*b.x+a.y*b.y+a.z*b.z+a.w*b.w;
  }
  if (lg<8){
    float4 a=q4[base4+32+lg], b=b4[base4+32+lg];
    acc+=a.x*b.x+a.y*b.y+a.z*b.z+a.w*b.w;
  }
  #pragma unroll
  for(int m=1;m<16;m<<=1) acc+=__shfl_xor(acc,m,64);
  if (lg==0)
    logits[(u32)e*8+hc0+hg]=(dotAA[(u32)src*8+hc0+hg]+acc)*INV160;
}

// ---------------------------------------------------------------- weight folding: (Wv,Wm) -> Wfold, Vfold
__global__ __launch_bounds__(256) void k_fold(
    const void* __restrict__ Wv_s, const void* __restrict__ Wv_v,
    const void* __restrict__ Wm_s, const void* __restrict__ Wm_v,
    const int* __restrict__ flags,
    float* __restrict__ Wfold, float* __restrict__ Vfold)
{
  const int fvs=flags[11], fvv=flags[12], fms=flags[13], fmv=flags[14];
  const int b=blockIdx.x, t=threadIdx.x;
  if (b<128){
    int idx=b*256+t;            // [0,32768)
    int i=idx>>6, o=idx&63;
    int h=i>>6, iin=i&63;
    float a=0.f;
    for(int d=0;d<64;d++)
      a += LD(Wv_s,(u32)iin*512 + h*64 + d, fvs) * LD(Wm_s,(u32)(h*64+d)*64 + o, fms);
    Wfold[idx]=a*0.0055242717280199026f;   // 0.125 * 1/sqrt(512)
  } else {
    int idx=(b-128)*256+t;      // [0,8192)
    int h=idx>>10, r=idx&1023, j2=r>>5, o2=r&31;
    float a=0.f;
    for(int dl=0;dl<32;dl++){
      int i2=h*32+dl;
      a += (LD(Wv_v,(u32)j2*256+i2,fvv)+LD(Wv_v,(u32)(32+j2)*256+i2,fvv))
           *LD(Wm_v,(u32)i2*32+o2,fmv);
    }
    Vfold[idx]=a*0.0078125f;               // 0.125 * 0.0625  (idx = h*1024 + j2*32 + o2)
  }
}

// ---------------------------------------------------------------- per-node pA/pB halves of the p-linear, 4 nodes/block
__global__ __launch_bounds__(256) void k_pprep(
    const void* __restrict__ X, const void* __restrict__ Wp_s,
    const void* __restrict__ Wp_v, const int* __restrict__ flags,
    float* __restrict__ pA, float* __restrict__ pB)
{
  __shared__ float xr[4][160];
  const int fX=flags[0], fps=flags[8], fpv=flags[9];
  const int t=threadIdx.x, n0=blockIdx.x*4;
  for(int u=t;u<640;u+=256){ int m=u/160,k=u-m*160; xr[m][k]=LD(X,(u32)(n0+m)*160+k,fX); }
  __syncthreads();
  if (t<64){
    const int j=t&31, half=t>>5;
    float a[4]={0.f,0.f,0.f,0.f};
    if (fps){
      const float* wp=(const float*)Wp_s;
      for(int i=0;i<64;i++){
        float w=wp[(u32)(half*64+i)*32+j];
        #pragma unroll
        for(int m=0;m<4;m++) a[m]+=xr[m][i]*w;
      }
    } else {
      for(int i=0;i<64;i++){
        float w=LD(Wp_s,(u32)(half*64+i)*32+j,fps);
        #pragma unroll
        for(int m=0;m<4;m++) a[m]+=xr[m][i]*w;
      }
    }
    float* d_ = half? pB:pA;
    #pragma unroll
    for(int m=0;m<4;m++) d_[(u32)(n0+m)*128+j]=a[m]*0.08838834764831845f;  // 1/sqrt(128)
  } else {
    const int idx=t-64;        // [0,192)
    const int half=idx/96;
    const int r=idx-half*96;   // [0,96)
    const int j=r/3, c=r-3*j;
    float a[4]={0.f,0.f,0.f,0.f};
    if (fpv){
      const float* wp=(const float*)Wp_v;
      for(int k=0;k<32;k++){
        float w=wp[(u32)(half*32+k)*32+j];
        #pragma unroll
        for(int m=0;m<4;m++) a[m]+=xr[m][64+k*3+c]*w;
      }
    } else {
      for(int k=0;k<32;k++){
        float w=LD(Wp_v,(u32)(half*32+k)*32+j,fpv);
        #pragma unroll
        for(int m=0;m<4;m++) a[m]+=xr[m][64+k*3+c]*w;
      }
    }
    float* d_ = half? pB:pA;
    #pragma unroll
    for(int m=0;m<4;m++) d_[(u32)(n0+m)*128+32+j*3+c]=a[m]*0.125f;         // 1/sqrt(64)
  }
}

// ---------------------------------------------------------------- CSR build (lives in dead imax/den buffers)
__global__ __launch_bounds__(256) void k_count(
    const void* __restrict__ ei, const int* __restrict__ flags,
    u32* __restrict__ cnt)
{
  int e = blockIdx.x*256 + threadIdx.x;
  int dst = LDI(ei,(u32)NE+e,flags[3]);
  atomicAdd(&cnt[dst],1u);
}
// single block: exclusive scan of 8192 counts -> offsets (+copy for cursor)
__global__ __launch_bounds__(256) void k_scan(
    u32* __restrict__ cnt, u32* __restrict__ off, u32* __restrict__ cur)
{
  __shared__ u32 s[NN];
  __shared__ u32 tsum[256];
  const int t=threadIdx.x;
  for(int u=t;u<NN;u+=256) s[u]=cnt[u];
  __syncthreads();
  const u32 base=(u32)t*32;
  u32 sum=0;
  for(int k=0;k<32;k++) sum+=s[base+k];
  tsum[t]=sum;
  __syncthreads();
  if(t==0){
    u32 run=0;
    for(int i=0;i<256;i++){ u32 v=tsum[i]; tsum[i]=run; run+=v; }
  }
  __syncthreads();
  u32 run=tsum[t];
  for(int k=0;k<32;k++){
    u32 v=s[base+k];
    off[base+k]=run; cur[base+k]=run;
    run+=v;
  }
  if(t==255) off[NN]=run;   // = NE
}
__global__ __launch_bounds__(256) void k_fill(
    const void* __restrict__ ei, const int* __restrict__ flags,
    u32* __restrict__ cur, u32* __restrict__ elist)
{
  int e = blockIdx.x*256 + threadIdx.x;
  int dst = LDI(ei,(u32)NE+e,flags[3]);
  u32 p = atomicAdd(&cur[dst],1u);
  elist[p] = (u32)e;
}

// ---------------------------------------------------------------- per-node: fused softmax + edge-u + gather + folded tail, 4 NODES/BLOCK
// attn weights computed once per lane and broadcast via shuffle (no logits reloads)
__global__ __launch_bounds__(256) void k_nodeval(
    const float* __restrict__ logits, const float* __restrict__ pA,
    const float* __restrict__ pBt,
    const u32* __restrict__ off, const u32* __restrict__ elist,
    const void* __restrict__ ei, const void* __restrict__ rbf,
    const void* __restrict__ rsh, const void* __restrict__ Wrbf,
    const float* __restrict__ Wfold, const float* __restrict__ Vfold,
    const void* __restrict__ ln_g, const void* __restrict__ ln_b,
    const void* __restrict__ W1, const void* __restrict__ b1,
    const void* __restrict__ W2, const void* __restrict__ b2,
    const int* __restrict__ flags, float* __restrict__ out)
{
  __shared__ float ag[4][1288];    // 20.6 KB, persists across phases (pad: 1288%32=8)
  __shared__ float smemf[4096];    // 16 KB overlay region
  // edge-phase aliases
  float* wrb = smemf;                                  // [1024]
  float (*pB4)[128]  = (float(*)[128])(smemf+1024);    // [4][128]
  float (*ubuf)[160] = (float(*)[160])(smemf+1536);    // [8][160] ends 2816
  // tail-phase aliases (padded partf)
  float (*partf)[4][65] = (float(*)[4][65])smemf;      // [4][4][65] ends 1040
  float (*partv)[192] = (float(*)[192])(smemf+1040);   // ends 1808
  float (*mrow)[160]  = (float(*)[160])(smemf+1808);   // ends 2448
  float (*n0_)[96]    = (float(*)[96])(smemf+2448);    // ends 2832
  float (*x1_)[96]    = (float(*)[96])(smemf+2832);    // ends 3216
  float (*y1_)[96]    = (float(*)[96])(smemf+3216);    // ends 3600
  float (*fl_)[96]    = (float(*)[96])(smemf+3600);    // ends 3984
  float* stat = smemf+3984;                            // mu[4], rstd[4]

  const int frb=flags[1], frs=flags[2], f64=flags[3], fwr=flags[10];
  const int fg=flags[15], fbb=flags[16], f1=flags[17], fb1=flags[18];
  const int f2=flags[19], fb2=flags[20];
  const int fastg = frb & frs;
  const int fastt = f1 & f2;
  const int t=threadIdx.x; const int g4=blockIdx.x*4;
  for(int u=t;u<1024;u+=256) wrb[u]=LD(Wrbf,u,fwr);
  #pragma unroll
  for(int m=0;m<4;m++) if (t<128) pB4[m][t]=pBt[(u32)(g4+m)*128+t];
  __syncthreads();

  const int h=t>>5, j=t&31;

  // -------- edge phase: loop over the block's 4 nodes
  for (int m=0;m<4;m++){
    const int n=g4+m;
    const u32 o0=off[n], o1=off[n+1];
    // fused scatter-softmax stats per (n,h): lane j caches edge o0+j's logit
    const u32 pidx=o0+j;
    const float lg = (pidx<o1) ? logits[(u32)elist[pidx]*8+h] : -3.4e38f;
    float mx=lg;
    for(u32 p=o0+32+j; p<o1; p+=32) mx=fmaxf(mx, logits[(u32)elist[p]*8+h]);
    #pragma unroll
    for(int s2=1;s2<32;s2<<=1) mx=fmaxf(mx, __shfl_xor(mx,s2,32));
    const float ex0 = (pidx<o1) ? __expf(lg-mx) : 0.f;
    float sm=ex0;
    for(u32 p=o0+32+j; p<o1; p+=32) sm+=__expf(logits[(u32)elist[p]*8+h]-mx);
    #pragma unroll
    for(int s2=1;s2<32;s2<<=1) sm+=__shfl_xor(sm,s2,32);
    const float winv=(sm>0.f)?1.f/sm:0.f;
    const float we = ex0*winv;     // attn weight for edge o0+j (this head)

    float a0=0.f,a1=0.f,a2=0.f,a3=0.f,a4=0.f;
    for (u32 base=o0; base<o1; base+=8){
      u32 rem=o1-base; int nb = rem<8u ? (int)rem : 8;
      if (h<nb){
        u32 e=elist[base+h];
        int src=LDI(ei,e,f64);
        const float* pa=pA+(u32)src*128;
        float ps  = pa[j]        + pB4[m][j];
        float pv0 = pa[32+j*3+0] + pB4[m][32+j*3+0];
        float pv1 = pa[32+j*3+1] + pB4[m][32+j*3+1];
        float pv2 = pa[32+j*3+2] + pB4[m][32+j*3+2];
        float scs=0.f, scv=0.f;
        float rs0,rs1,rs2,rs3;
        if (fastg){
          const float* rb=(const float*)rbf + (size_t)e*16;
          #pragma unroll
          for(int r=0;r<16;r++){
            float x=rb[r];
            scs+=x*wrb[r*64+j]; scv+=x*wrb[r*64+32+j];
          }
          const float* rs=(const float*)rsh + (size_t)e*128;
          rs0=rs[j]; rs1=rs[32+j*3+0]; rs2=rs[32+j*3+1]; rs3=rs[32+j*3+2];
        } else {
          for(int r=0;r<16;r++){
            float x=LD(rbf,(u32)e*16+r,frb);
            scs+=x*wrb[r*64+j]; scv+=x*wrb[r*64+32+j];
          }
          rs0=LD(rsh,(u32)e*128+j,frs);
          rs1=LD(rsh,(u32)e*128+32+j*3+0,frs);
          rs2=LD(rsh,(u32)e*128+32+j*3+1,frs);
          rs3=LD(rsh,(u32)e*128+32+j*3+2,frs);
        }
        float ss = rs0 * scs * ps;
        float v0 = rs1 * scv * pv0;
        float v1 = rs2 * scv * pv1;
        float v2 = rs3 * scv * pv2;
        ubuf[h][j]        = ss*ss;
        ubuf[h][32+j]     = (v0*v0+v1*v1+v2*v2)*0.57735026918962576f;
        ubuf[h][64+3*j+0] = ss*v0;
        ubuf[h][64+3*j+1] = ss*v1;
        ubuf[h][64+3*j+2] = ss*v2;
      }
      __syncthreads();
      const int off0=(int)(base-o0);
      for(int q=0;q<nb;q++){
        const int idx=off0+q;
        float w;
        if (idx<32) w=__shfl(we, idx, 32);
        else        w=__expf(logits[(u32)elist[base+q]*8+h]-mx)*winv;
        a0+=w*ubuf[q][j];        a1+=w*ubuf[q][32+j];
        a2+=w*ubuf[q][64+3*j+0]; a3+=w*ubuf[q][64+3*j+1]; a4+=w*ubuf[q][64+3*j+2];
      }
      __syncthreads();
    }
    ag[m][h*64+j]=a0; ag[m][h*64+32+j]=a1;
    ag[m][512+h*96+3*j+0]=a2; ag[m][512+h*96+3*j+1]=a3; ag[m][512+h*96+3*j+2]=a4;
  }
  __syncthreads();   // edge-phase LDS dead; tail overlay begins

  // -------- folded scalar path: thread (o4=t&15, pp=t>>4): m=pp&3, i-group gq=pp>>2
  {
    const int o4=t&15, pp=t>>4;
    const int m=pp&3, gq=pp>>2;
    const float4* Wf4=(const float4*)Wfold;
    float ax=0.f,ay=0.f,az=0.f,aw=0.f;
    const int i0=gq*128;
    for(int i=i0;i<i0+128;i++){
      float a=ag[m][i];
      float4 wv=Wf4[(u32)i*16+o4];
      ax+=a*wv.x; ay+=a*wv.y; az+=a*wv.z; aw+=a*wv.w;
    }
    partf[gq][m][o4*4+0]=ax; partf[gq][m][o4*4+1]=ay;
    partf[gq][m][o4*4+2]=az; partf[gq][m][o4*4+3]=aw;
  }
  // folded vector path: loads shared across the 4 nodes
  if (t<192){
    const int o2=t&31, c=(t>>5)%3, p=t/96;
    float a[4]={0.f,0.f,0.f,0.f};
    for(int hh=p*4;hh<p*4+4;hh++)
      for(int j2=0;j2<32;j2++){
        float v=Vfold[(u32)hh*1024+j2*32+o2];
        #pragma unroll
        for(int m=0;m<4;m++) a[m]+=ag[m][512+hh*96+j2*3+c]*v;
      }
    #pragma unroll
    for(int m=0;m<4;m++) partv[m][t]=a[m];
  }
  __syncthreads();
  {
    const int o=t&63, m=t>>6;
    mrow[m][o]=partf[0][m][o]+partf[1][m][o]+partf[2][m][o]+partf[3][m][o];
  }
  if (t<96){
    #pragma unroll
    for(int m=0;m<4;m++)
      mrow[m][64+(t&31)*3+(t>>5)]=partv[m][t]+partv[m][t+96];
  }
  __syncthreads();

  if (t<96){
    #pragma unroll
    for(int m=0;m<4;m++){
      float val;
      if (t<64) val=fabsf(mrow[m][t]);
      else { int o2=t-64;
        float a=mrow[m][64+o2*3],b=mrow[m][64+o2*3+1],c=mrow[m][64+o2*3+2];
        val=sqrtf(a*a+b*b+c*c); }
      n0_[m][t]=val;
    }
  }
  __syncthreads();
  {
    const int m=t>>6;
    float mu=0.f,ss2=0.f;
    for(int i=0;i<96;i++){ float v=n0_[m][i]; mu+=v; ss2+=v*v; }
    mu*=(1.f/96.f);
    float var=fmaxf(ss2*(1.f/96.f)-mu*mu,0.f);
    float rstd=rsqrtf(var+1e-5f);
    if ((t&63)==0){ stat[m]=mu; stat[4+m]=rstd; }
  }
  __syncthreads();
  if (t<96){
    float gv = fg  ? ((const float*)ln_g)[t] : LD(ln_g,t,fg);
    float bv = fbb ? ((const float*)ln_b)[t] : LD(ln_b,t,fbb);
    #pragma unroll
    for(int m=0;m<4;m++)
      x1_[m][t]=(n0_[m][t]-stat[m])*stat[4+m]*gv+bv;
  }
  __syncthreads();
  if (t<96){
    float bb = fb1 ? ((const float*)b1)[t] : LD(b1,t,fb1);
    float a[4]={bb,bb,bb,bb};
    if (fastt){
      const float* w1=(const float*)W1;
      for(int i=0;i<96;i++){
        float w=w1[(u32)i*96+t];          // lane-coalesced over t
        #pragma unroll
        for(int m=0;m<4;m++) a[m]+=x1_[m][i]*w;
      }
    } else {
      for(int i=0;i<96;i++){
        float w=LD(W1,i*96+t,f1);
        #pragma unroll
        for(int m=0;m<4;m++) a[m]+=x1_[m][i]*w;
      }
    }
    #pragma unroll
    for(int m=0;m<4;m++) y1_[m][t]=a[m]/(1.f+__expf(-a[m]));      // silu
  }
  __syncthreads();
  if (t<96){
    float bb = fb2 ? ((const float*)b2)[t] : LD(b2,t,fb2);
    float a[4]={bb,bb,bb,bb};
    if (fastt){
      const float* w2=(const float*)W2;
      for(int i=0;i<96;i++){
        float w=w2[(u32)i*96+t];
        #pragma unroll
        for(int m=0;m<4;m++) a[m]+=y1_[m][i]*w;
      }
    } else {
      for(int i=0;i<96;i++){
        float w=LD(W2,i*96+t,f2);
        #pragma unroll
        for(int m=0;m<4;m++) a[m]+=y1_[m][i]*w;
      }
    }
    #pragma unroll
    for(int m=0;m<4;m++){
      float gg=a[m]/(1.f+__expf(-a[m]));
      fl_[m][t]=gg/(n0_[m][t]+1e-6f);
    }
  }
  __syncthreads();
  if (t<160){
    #pragma unroll
    for(int m=0;m<4;m++){
      float v;
      if (t<64) v=mrow[m][t]*fl_[m][t];
      else { int q=t-64; int o2=q/3; v=mrow[m][t]*fl_[m][64+o2]; }
      out[(u32)(g4+m)*160+t]=v;
    }
  }
}

// ---------------------------------------------------------------- launch
extern "C" void kernel_launch(void* const* d_in, const int* in_sizes, int n_in,
                              void* d_out, int out_size, void* d_ws, size_t ws_size,
                              hipStream_t stream)
{
  (void)in_sizes; (void)n_in;
  const void* X    = d_in[0];
  const void* rbf  = d_in[1];
  const void* rsh  = d_in[2];
  const void* ei   = d_in[3];
  const void* Wq_s = d_in[4];
  const void* Wq_v = d_in[5];
  const void* Wk_s = d_in[6];
  const void* Wk_v = d_in[7];
  const void* Wp_s = d_in[8];
  const void* Wp_v = d_in[9];
  const void* Wrbf = d_in[10];
  const void* Wv_s = d_in[11];
  const void* Wv_v = d_in[12];
  const void* Wm_s = d_in[13];
  const void* Wm_v = d_in[14];
  const void* ln_g = d_in[15];
  const void* ln_b = d_in[16];
  const void* W1   = d_in[17];
  const void* b1   = d_in[18];
  const void* W2   = d_in[19];
  const void* b2   = d_in[20];

  // ws layout (~44.5 MB) — identical footprint to the passing baseline
  char* w = (char*)d_ws;
  int* flags     = (int*)w;   w += 256;
  float* logits  = (float*)w; w += (size_t)NE*8*4;   // raw logits (softmax fused in nodeval)
  u32* imax      = (u32*)w;   w += (size_t)NN*8*4;   // CSR off/cur + Wfold/Vfold
  float* den     = (float*)w; w += (size_t)NN*8*4;   // CSR edge list
  char* uni = w;              w += (size_t)NN*1280*4;
  // uni phase 1: qtab | kbtab (4-head chunk tables, exact fit);
  // phase 2: pA | pB (overlay dead qtab)
  float* qtab  = (float*)uni;
  float* kbtab = (float*)(uni + (size_t)NN*640*4);
  float* pA    = (float*)uni;
  float* pB    = (float*)(uni + (size_t)NN*128*4);
  // imax sub-layout:
  //   [0, 32772)        csr counts -> csr_off (NN+1 u32)
  //   [49152, 81920)    csr_cur (NN u32)
  //   [98304, 229376)   Wfold (512*64 f32 = 128KB)
  //   [229376, 262144)  Vfold (8*32*32 f32 = 32KB)
  u32* csr_off = imax;
  u32* csr_cur = imax + 12288;
  float* Wfold = (float*)((char*)imax + 98304);
  float* Vfold = (float*)((char*)imax + 229376);
  u32* elist   = (u32*)den;            // NE u32 = 256KB exact
  // dotAA[NN][8] scratch lives in d_out (fully overwritten by k_nodeval)
  float* dotAA = (float*)d_out;
  size_t required = (size_t)(w - (char*)d_ws);

  if (ws_size < required){
    k_sentinel<<<(out_size+255)/256,256,0,stream>>>((float*)d_out, out_size);
    return;
  }

  k_detect<<<1,64,0,stream>>>(X,rbf,rsh,ei,Wq_s,Wq_v,Wk_s,Wk_v,Wp_s,Wp_v,
                              Wrbf,Wv_s,Wv_v,Wm_s,Wm_v,ln_g,ln_b,W1,b1,W2,b2,flags);
  // weight folding + CSR build
  k_fold<<<160,256,0,stream>>>(Wv_s,Wv_v,Wm_s,Wm_v,flags,Wfold,Vfold);
  hipMemsetAsync(imax, 0, (size_t)NN*4, stream);                 // counts = 0
  k_count<<<NE/256,256,0,stream>>>(ei,flags,imax);
  k_scan<<<1,256,0,stream>>>(imax,csr_off,csr_cur);
  k_fill<<<NE/256,256,0,stream>>>(ei,flags,csr_cur,elist);
  // 2 head-chunks (4 heads each): 4-node prep (head-major tables) then elist-grouped logits
  for (int c=0;c<2;c++){
    k_prep4<<<NN/4,384,0,stream>>>(X,Wq_s,Wq_v,Wk_s,Wk_v,flags,c*4,qtab,kbtab,dotAA);
    k_elog4<<<NE/8,512,0,stream>>>(ei,flags,qtab,kbtab,dotAA,elist,c*4,logits);
  }
  // phase 2: per-node p-halves (4 nodes/block, overlay dead tables), then fused softmax+gather+tail
  k_pprep<<<NN/4,256,0,stream>>>(X,Wp_s,Wp_v,flags,pA,pB);
  k_nodeval<<<NN/4,256,0,stream>>>(logits,pA,pB,csr_off,elist,ei,rbf,rsh,Wrbf,
                                   Wfold,Vfold,ln_g,ln_b,W1,b1,W2,b2,flags,(float*)d_out);
}

// Round 16
// 402.099 us; speedup vs baseline: 1.1653x; 1.0134x over previous
//
#include <hip/hip_runtime.h>

typedef unsigned short u16;
typedef unsigned int u32;

#define NN 8192
#define NE 65536
#define INV160 0.07905694150420949f   // 1/sqrt(160)

__device__ __forceinline__ float BF(u16 u){ return __uint_as_float(((u32)u)<<16); }
// dual-dtype load: f=1 -> f32, f=0 -> bf16
__device__ __forceinline__ float LD(const void* p, u32 i, int f){
  return f ? ((const float*)p)[i] : BF(((const u16*)p)[i]);
}
// dual int load: f64=1 -> int64, else int32
__device__ __forceinline__ int LDI(const void* p, u32 i, int f64){
  return f64 ? (int)((const long long*)p)[i] : ((const int*)p)[i];
}

// ---------------------------------------------------------------- per-buffer dtype detect
__global__ void k_detect(
    const void* b0, const void* b1, const void* b2, const void* b3,
    const void* b4, const void* b5, const void* b6, const void* b7,
    const void* b8, const void* b9, const void* b10, const void* b11,
    const void* b12, const void* b13, const void* b14, const void* b15,
    const void* b16, const void* b17, const void* b18, const void* b19,
    const void* b20, int* flags)
{
  const void* bufs[21] = {b0,b1,b2,b3,b4,b5,b6,b7,b8,b9,b10,
                          b11,b12,b13,b14,b15,b16,b17,b18,b19,b20};
  int i = threadIdx.x;
  if (i >= 21) return;
  const u32* w = (const u32*)bufs[i];
  if (i == 3){
    int allz = 1;
    for (int k=0;k<32;k++) if (w[2*k+1] != 0u) allz = 0;
    flags[3] = allz;             // 1 = int64
  } else {
    int cnt = 0;
    for (int k=0;k<40;k++){
      u32 lo = w[k] & 0xFFFFu;
      u32 e = (lo>>7)&0xFFu;
      if (e>=123u && e<=131u) cnt++;
    }
    flags[i] = (cnt>=20) ? 0 : 1;  // 0=bf16, 1=f32
  }
}

__global__ void k_sentinel(float* __restrict__ out, int n){
  int i = blockIdx.x*256+threadIdx.x;
  if (i<n) out[i] = 12345.0f;
}

// ---------------------------------------------------------------- per-node prep for one head-chunk (4 heads), 4 nodes/block
// qtab/kbtab per node 640 floats, HEAD-MAJOR: [local head][160] = [0..64) scalar d, [64..160) 3*j+c
// dotAA[n][8] (in d_out scratch): q.kA per head
__global__ __launch_bounds__(384) void k_prep4(
    const void* __restrict__ X, const void* __restrict__ Wq_s,
    const void* __restrict__ Wq_v, const void* __restrict__ Wk_s,
    const void* __restrict__ Wk_v, const int* __restrict__ flags,
    int hc0, float* __restrict__ qtab, float* __restrict__ kbtab,
    float* __restrict__ dotAA)
{
  __shared__ float xr[4][160];
  __shared__ float dsum[4][4];   // [node][local head]
  const int fX=flags[0], fqs=flags[4], fqv=flags[5], fks=flags[6], fkv=flags[7];
  const int fall = fqs & fqv & fks & fkv;
  const int t=threadIdx.x; const int n0=blockIdx.x*4;
  for(int u=t;u<640;u+=384){ int m=u/160,k=u-m*160; xr[m][k]=LD(X,(u32)(n0+m)*160+k,fX); }
  if (t<16) dsum[t>>2][t&3]=0.f;
  __syncthreads();
  if (t<256){
    // scalar outputs: local head lh=t>>6, dim d=t&63; o = hc0*64 + t
    const int lh=t>>6, d=t&63;
    const int o=hc0*64+t;
    float q[4]={0,0,0,0}, ka[4]={0,0,0,0}, kb[4]={0,0,0,0};
    if (fall){
      const float* wqs=(const float*)Wq_s;
      const float* wks=(const float*)Wk_s;
      for(int i=0;i<64;i++){
        float wq=wqs[(u32)i*512+o], wa=wks[(u32)i*512+o], wb=wks[(u32)(64+i)*512+o];
        #pragma unroll
        for(int m=0;m<4;m++){ float s=xr[m][i]; q[m]+=s*wq; ka[m]+=s*wa; kb[m]+=s*wb; }
      }
    } else {
      for(int i=0;i<64;i++){
        float wq=LD(Wq_s,(u32)i*512+o,fqs);
        float wa=LD(Wk_s,(u32)i*512+o,fks);
        float wb=LD(Wk_s,(u32)(64+i)*512+o,fks);
        #pragma unroll
        for(int m=0;m<4;m++){ float s=xr[m][i]; q[m]+=s*wq; ka[m]+=s*wa; kb[m]+=s*wb; }
      }
    }
    #pragma unroll
    for(int m=0;m<4;m++){
      float qs = q[m]*0.125f;                    // 1/sqrt(64)
      float kas= ka[m]*0.08838834764831845f;     // 1/sqrt(128)
      float kbs= kb[m]*0.08838834764831845f;
      u32 base=(u32)(n0+m)*640 + lh*160 + d;     // head-major
      qtab [base]=qs;
      kbtab[base]=kbs;
      float dd=qs*kas;
      for(int s2=1;s2<64;s2<<=1) dd+=__shfl_xor(dd,s2,64);
      if(d==0) atomicAdd(&dsum[m][lh],dd);
    }
  } else {
    // vector outputs: ol in [0,128), local head lh=ol>>5, j=ol&31; ov = hc0*32 + ol
    const int ol=t-256;
    const int lh=ol>>5, jj=ol&31;
    const int o=hc0*32+ol;
    float q[4][3]={}, ka[4][3]={}, kb[4][3]={};
    if (fall){
      const float* wqv=(const float*)Wq_v;
      const float* wkv=(const float*)Wk_v;
      for(int j=0;j<32;j++){
        float wq=wqv[(u32)j*256+o], wa=wkv[(u32)j*256+o], wb=wkv[(u32)(32+j)*256+o];
        #pragma unroll
        for(int m=0;m<4;m++){
          #pragma unroll
          for(int c=0;c<3;c++){
            float x=xr[m][64+j*3+c];
            q[m][c]+=x*wq; ka[m][c]+=x*wa; kb[m][c]+=x*wb;
          }
        }
      }
    } else {
      for(int j=0;j<32;j++){
        float wq=LD(Wq_v,(u32)j*256+o,fqv);
        float wa=LD(Wk_v,(u32)j*256+o,fkv);
        float wb=LD(Wk_v,(u32)(32+j)*256+o,fkv);
        #pragma unroll
        for(int m=0;m<4;m++){
          #pragma unroll
          for(int c=0;c<3;c++){
            float x=xr[m][64+j*3+c];
            q[m][c]+=x*wq; ka[m][c]+=x*wa; kb[m][c]+=x*wb;
          }
        }
      }
    }
    const float sq=0.17677669529663687f;   // 1/sqrt(32)
    const float sk=0.125f;                 // 1/sqrt(64)
    #pragma unroll
    for(int m=0;m<4;m++){
      float dd=0.f;
      u32 base=(u32)(n0+m)*640 + lh*160 + 64 + (u32)jj*3;   // head-major
      #pragma unroll
      for(int c=0;c<3;c++){
        float qs=q[m][c]*sq, kas=ka[m][c]*sk, kbs=kb[m][c]*sk;
        qtab[base+c]=qs; kbtab[base+c]=kbs;
        dd+=qs*kas;
      }
      for(int s2=1;s2<32;s2<<=1) dd+=__shfl_xor(dd,s2,64);
      if((t&31)==0) atomicAdd(&dsum[m][lh],dd);
    }
  }
  __syncthreads();
  if (t<16){ int m=t>>2, hh=t&3; dotAA[(u32)(n0+m)*8+hc0+hh]=dsum[m][hh]; }
}

// ---------------------------------------------------------------- per-edge logits for one 4-head chunk
// 8 edges/block via elist, 1 wave/edge; head-major tables: 16 lanes per head,
// 40 contiguous float4 per head, single-accumulator 4-level reduce.
// LOGITS ARE WRITTEN IN ELIST (POSITION) ORDER: logits[p*8+h], p = slot in elist.
__global__ __launch_bounds__(512) void k_elog4(
    const void* __restrict__ ei, const int* __restrict__ flags,
    const float* __restrict__ qtab, const float* __restrict__ kbtab,
    const float* __restrict__ dotAA, const u32* __restrict__ elist,
    int hc0, float* __restrict__ logits)
{
  const int f64=flags[3];
  const int t=threadIdx.x;
  const u32 pp=(u32)blockIdx.x*8+(t>>6);
  const int e=(int)elist[pp], l=t&63;
  const int src=LDI(ei,(u32)e,f64);
  const int dst=LDI(ei,(u32)NE+e,f64);
  const float4* q4=(const float4*)qtab + (u32)src*160;
  const float4* b4=(const float4*)kbtab + (u32)dst*160;
  const int hg=l>>4, lg=l&15;
  const int base4=hg*40;
  float acc;
  {
    float4 a=q4[base4+lg], b=b4[base4+lg];
    acc=a.x*b.x+a.y*b.y+a.z*b.z+a.w*b.w;
  }
  {
    float4 a=q4[base4+16+lg], b=b4[base4+16+lg];
    acc+=a.x*b.x+a.y*b.y+a.z*b.z+a.w*b.w;
  }
  if (lg<8){
    float4 a=q4[base4+32+lg], b=b4[base4+32+lg];
    acc+=a.x*b.x+a.y*b.y+a.z*b.z+a.w*b.w;
  }
  #pragma unroll
  for(int m=1;m<16;m<<=1) acc+=__shfl_xor(acc,m,64);
  if (lg==0)
    logits[pp*8+hc0+hg]=(dotAA[(u32)src*8+hc0+hg]+acc)*INV160;
}

// ---------------------------------------------------------------- weight folding: (Wv,Wm) -> Wfold, Vfold
__global__ __launch_bounds__(256) void k_fold(
    const void* __restrict__ Wv_s, const void* __restrict__ Wv_v,
    const void* __restrict__ Wm_s, const void* __restrict__ Wm_v,
    const int* __restrict__ flags,
    float* __restrict__ Wfold, float* __restrict__ Vfold)
{
  const int fvs=flags[11], fvv=flags[12], fms=flags[13], fmv=flags[14];
  const int b=blockIdx.x, t=threadIdx.x;
  if (b<128){
    int idx=b*256+t;            // [0,32768)
    int i=idx>>6, o=idx&63;
    int h=i>>6, iin=i&63;
    float a=0.f;
    for(int d=0;d<64;d++)
      a += LD(Wv_s,(u32)iin*512 + h*64 + d, fvs) * LD(Wm_s,(u32)(h*64+d)*64 + o, fms);
    Wfold[idx]=a*0.0055242717280199026f;   // 0.125 * 1/sqrt(512)
  } else {
    int idx=(b-128)*256+t;      // [0,8192)
    int h=idx>>10, r=idx&1023, j2=r>>5, o2=r&31;
    float a=0.f;
    for(int dl=0;dl<32;dl++){
      int i2=h*32+dl;
      a += (LD(Wv_v,(u32)j2*256+i2,fvv)+LD(Wv_v,(u32)(32+j2)*256+i2,fvv))
           *LD(Wm_v,(u32)i2*32+o2,fmv);
    }
    Vfold[idx]=a*0.0078125f;               // 0.125 * 0.0625  (idx = h*1024 + j2*32 + o2)
  }
}

// ---------------------------------------------------------------- per-node pA/pB halves of the p-linear, 4 nodes/block
__global__ __launch_bounds__(256) void k_pprep(
    const void* __restrict__ X, const void* __restrict__ Wp_s,
    const void* __restrict__ Wp_v, const int* __restrict__ flags,
    float* __restrict__ pA, float* __restrict__ pB)
{
  __shared__ float xr[4][160];
  const int fX=flags[0], fps=flags[8], fpv=flags[9];
  const int t=threadIdx.x, n0=blockIdx.x*4;
  for(int u=t;u<640;u+=256){ int m=u/160,k=u-m*160; xr[m][k]=LD(X,(u32)(n0+m)*160+k,fX); }
  __syncthreads();
  if (t<64){
    const int j=t&31, half=t>>5;
    float a[4]={0.f,0.f,0.f,0.f};
    if (fps){
      const float* wp=(const float*)Wp_s;
      for(int i=0;i<64;i++){
        float w=wp[(u32)(half*64+i)*32+j];
        #pragma unroll
        for(int m=0;m<4;m++) a[m]+=xr[m][i]*w;
      }
    } else {
      for(int i=0;i<64;i++){
        float w=LD(Wp_s,(u32)(half*64+i)*32+j,fps);
        #pragma unroll
        for(int m=0;m<4;m++) a[m]+=xr[m][i]*w;
      }
    }
    float* d_ = half? pB:pA;
    #pragma unroll
    for(int m=0;m<4;m++) d_[(u32)(n0+m)*128+j]=a[m]*0.08838834764831845f;  // 1/sqrt(128)
  } else {
    const int idx=t-64;        // [0,192)
    const int half=idx/96;
    const int r=idx-half*96;   // [0,96)
    const int j=r/3, c=r-3*j;
    float a[4]={0.f,0.f,0.f,0.f};
    if (fpv){
      const float* wp=(const float*)Wp_v;
      for(int k=0;k<32;k++){
        float w=wp[(u32)(half*32+k)*32+j];
        #pragma unroll
        for(int m=0;m<4;m++) a[m]+=xr[m][64+k*3+c]*w;
      }
    } else {
      for(int k=0;k<32;k++){
        float w=LD(Wp_v,(u32)(half*32+k)*32+j,fpv);
        #pragma unroll
        for(int m=0;m<4;m++) a[m]+=xr[m][64+k*3+c]*w;
      }
    }
    float* d_ = half? pB:pA;
    #pragma unroll
    for(int m=0;m<4;m++) d_[(u32)(n0+m)*128+32+j*3+c]=a[m]*0.125f;         // 1/sqrt(64)
  }
}

// ---------------------------------------------------------------- CSR build (lives in dead imax/den buffers)
__global__ __launch_bounds__(256) void k_count(
    const void* __restrict__ ei, const int* __restrict__ flags,
    u32* __restrict__ cnt)
{
  int e = blockIdx.x*256 + threadIdx.x;
  int dst = LDI(ei,(u32)NE+e,flags[3]);
  atomicAdd(&cnt[dst],1u);
}
// single block: exclusive scan of 8192 counts -> offsets (+copy for cursor)
__global__ __launch_bounds__(256) void k_scan(
    u32* __restrict__ cnt, u32* __restrict__ off, u32* __restrict__ cur)
{
  __shared__ u32 s[NN];
  __shared__ u32 tsum[256];
  const int t=threadIdx.x;
  for(int u=t;u<NN;u+=256) s[u]=cnt[u];
  __syncthreads();
  const u32 base=(u32)t*32;
  u32 sum=0;
  for(int k=0;k<32;k++) sum+=s[base+k];
  tsum[t]=sum;
  __syncthreads();
  if(t==0){
    u32 run=0;
    for(int i=0;i<256;i++){ u32 v=tsum[i]; tsum[i]=run; run+=v; }
  }
  __syncthreads();
  u32 run=tsum[t];
  for(int k=0;k<32;k++){
    u32 v=s[base+k];
    off[base+k]=run; cur[base+k]=run;
    run+=v;
  }
  if(t==255) off[NN]=run;   // = NE
}
__global__ __launch_bounds__(256) void k_fill(
    const void* __restrict__ ei, const int* __restrict__ flags,
    u32* __restrict__ cur, u32* __restrict__ elist)
{
  int e = blockIdx.x*256 + threadIdx.x;
  int dst = LDI(ei,(u32)NE+e,flags[3]);
  u32 p = atomicAdd(&cur[dst],1u);
  elist[p] = (u32)e;
}

// ---------------------------------------------------------------- per-node: fused softmax + edge-u + gather + folded tail, 4 NODES/BLOCK
// logits are position-indexed (elist order) -> all softmax reads coalesced
__global__ __launch_bounds__(256) void k_nodeval(
    const float* __restrict__ logits, const float* __restrict__ pA,
    const float* __restrict__ pBt,
    const u32* __restrict__ off, const u32* __restrict__ elist,
    const void* __restrict__ ei, const void* __restrict__ rbf,
    const void* __restrict__ rsh, const void* __restrict__ Wrbf,
    const float* __restrict__ Wfold, const float* __restrict__ Vfold,
    const void* __restrict__ ln_g, const void* __restrict__ ln_b,
    const void* __restrict__ W1, const void* __restrict__ b1,
    const void* __restrict__ W2, const void* __restrict__ b2,
    const int* __restrict__ flags, float* __restrict__ out)
{
  __shared__ float ag[4][1288];    // 20.6 KB, persists across phases (pad: 1288%32=8)
  __shared__ float smemf[4096];    // 16 KB overlay region
  // edge-phase aliases
  float* wrb = smemf;                                  // [1024]
  float (*pB4)[128]  = (float(*)[128])(smemf+1024);    // [4][128]
  float (*ubuf)[160] = (float(*)[160])(smemf+1536);    // [8][160] ends 2816
  // tail-phase aliases (padded partf)
  float (*partf)[4][65] = (float(*)[4][65])smemf;      // [4][4][65] ends 1040
  float (*partv)[192] = (float(*)[192])(smemf+1040);   // ends 1808
  float (*mrow)[160]  = (float(*)[160])(smemf+1808);   // ends 2448
  float (*n0_)[96]    = (float(*)[96])(smemf+2448);    // ends 2832
  float (*x1_)[96]    = (float(*)[96])(smemf+2832);    // ends 3216
  float (*y1_)[96]    = (float(*)[96])(smemf+3216);    // ends 3600
  float (*fl_)[96]    = (float(*)[96])(smemf+3600);    // ends 3984
  float* stat = smemf+3984;                            // mu[4], rstd[4]

  const int frb=flags[1], frs=flags[2], f64=flags[3], fwr=flags[10];
  const int fg=flags[15], fbb=flags[16], f1=flags[17], fb1=flags[18];
  const int f2=flags[19], fb2=flags[20];
  const int fastg = frb & frs;
  const int fastt = f1 & f2;
  const int t=threadIdx.x; const int g4=blockIdx.x*4;
  for(int u=t;u<1024;u+=256) wrb[u]=LD(Wrbf,u,fwr);
  #pragma unroll
  for(int m=0;m<4;m++) if (t<128) pB4[m][t]=pBt[(u32)(g4+m)*128+t];
  __syncthreads();

  const int h=t>>5, j=t&31;

  // -------- edge phase: loop over the block's 4 nodes
  for (int m=0;m<4;m++){
    const int n=g4+m;
    const u32 o0=off[n], o1=off[n+1];
    // fused scatter-softmax stats per (n,h): coalesced position-indexed reads
    const u32 pidx=o0+j;
    const float lg = (pidx<o1) ? logits[pidx*8+h] : -3.4e38f;
    float mx=lg;
    for(u32 p=o0+32+j; p<o1; p+=32) mx=fmaxf(mx, logits[p*8+h]);
    #pragma unroll
    for(int s2=1;s2<32;s2<<=1) mx=fmaxf(mx, __shfl_xor(mx,s2,32));
    const float ex0 = (pidx<o1) ? __expf(lg-mx) : 0.f;
    float sm=ex0;
    for(u32 p=o0+32+j; p<o1; p+=32) sm+=__expf(logits[p*8+h]-mx);
    #pragma unroll
    for(int s2=1;s2<32;s2<<=1) sm+=__shfl_xor(sm,s2,32);
    const float winv=(sm>0.f)?1.f/sm:0.f;
    const float we = ex0*winv;     // attn weight for edge at position o0+j (this head)

    float a0=0.f,a1=0.f,a2=0.f,a3=0.f,a4=0.f;
    for (u32 base=o0; base<o1; base+=8){
      u32 rem=o1-base; int nb = rem<8u ? (int)rem : 8;
      if (h<nb){
        u32 e=elist[base+h];
        int src=LDI(ei,e,f64);
        const float* pa=pA+(u32)src*128;
        float ps  = pa[j]        + pB4[m][j];
        float pv0 = pa[32+j*3+0] + pB4[m][32+j*3+0];
        float pv1 = pa[32+j*3+1] + pB4[m][32+j*3+1];
        float pv2 = pa[32+j*3+2] + pB4[m][32+j*3+2];
        float scs=0.f, scv=0.f;
        float rs0,rs1,rs2,rs3;
        if (fastg){
          const float* rb=(const float*)rbf + (size_t)e*16;
          #pragma unroll
          for(int r=0;r<16;r++){
            float x=rb[r];
            scs+=x*wrb[r*64+j]; scv+=x*wrb[r*64+32+j];
          }
          const float* rs=(const float*)rsh + (size_t)e*128;
          rs0=rs[j]; rs1=rs[32+j*3+0]; rs2=rs[32+j*3+1]; rs3=rs[32+j*3+2];
        } else {
          for(int r=0;r<16;r++){
            float x=LD(rbf,(u32)e*16+r,frb);
            scs+=x*wrb[r*64+j]; scv+=x*wrb[r*64+32+j];
          }
          rs0=LD(rsh,(u32)e*128+j,frs);
          rs1=LD(rsh,(u32)e*128+32+j*3+0,frs);
          rs2=LD(rsh,(u32)e*128+32+j*3+1,frs);
          rs3=LD(rsh,(u32)e*128+32+j*3+2,frs);
        }
        float ss = rs0 * scs * ps;
        float v0 = rs1 * scv * pv0;
        float v1 = rs2 * scv * pv1;
        float v2 = rs3 * scv * pv2;
        ubuf[h][j]        = ss*ss;
        ubuf[h][32+j]     = (v0*v0+v1*v1+v2*v2)*0.57735026918962576f;
        ubuf[h][64+3*j+0] = ss*v0;
        ubuf[h][64+3*j+1] = ss*v1;
        ubuf[h][64+3*j+2] = ss*v2;
      }
      __syncthreads();
      const int off0=(int)(base-o0);
      for(int q=0;q<nb;q++){
        const int idx=off0+q;
        float w;
        if (idx<32) w=__shfl(we, idx, 32);
        else        w=__expf(logits[(base+q)*8+h]-mx)*winv;
        a0+=w*ubuf[q][j];        a1+=w*ubuf[q][32+j];
        a2+=w*ubuf[q][64+3*j+0]; a3+=w*ubuf[q][64+3*j+1]; a4+=w*ubuf[q][64+3*j+2];
      }
      __syncthreads();
    }
    ag[m][h*64+j]=a0; ag[m][h*64+32+j]=a1;
    ag[m][512+h*96+3*j+0]=a2; ag[m][512+h*96+3*j+1]=a3; ag[m][512+h*96+3*j+2]=a4;
  }
  __syncthreads();   // edge-phase LDS dead; tail overlay begins

  // -------- folded scalar path: thread (o4=t&15, pp=t>>4): m=pp&3, i-group gq=pp>>2
  {
    const int o4=t&15, pp=t>>4;
    const int m=pp&3, gq=pp>>2;
    const float4* Wf4=(const float4*)Wfold;
    float ax=0.f,ay=0.f,az=0.f,aw=0.f;
    const int i0=gq*128;
    for(int i=i0;i<i0+128;i++){
      float a=ag[m][i];
      float4 wv=Wf4[(u32)i*16+o4];
      ax+=a*wv.x; ay+=a*wv.y; az+=a*wv.z; aw+=a*wv.w;
    }
    partf[gq][m][o4*4+0]=ax; partf[gq][m][o4*4+1]=ay;
    partf[gq][m][o4*4+2]=az; partf[gq][m][o4*4+3]=aw;
  }
  // folded vector path: loads shared across the 4 nodes
  if (t<192){
    const int o2=t&31, c=(t>>5)%3, p=t/96;
    float a[4]={0.f,0.f,0.f,0.f};
    for(int hh=p*4;hh<p*4+4;hh++)
      for(int j2=0;j2<32;j2++){
        float v=Vfold[(u32)hh*1024+j2*32+o2];
        #pragma unroll
        for(int m=0;m<4;m++) a[m]+=ag[m][512+hh*96+j2*3+c]*v;
      }
    #pragma unroll
    for(int m=0;m<4;m++) partv[m][t]=a[m];
  }
  __syncthreads();
  {
    const int o=t&63, m=t>>6;
    mrow[m][o]=partf[0][m][o]+partf[1][m][o]+partf[2][m][o]+partf[3][m][o];
  }
  if (t<96){
    #pragma unroll
    for(int m=0;m<4;m++)
      mrow[m][64+(t&31)*3+(t>>5)]=partv[m][t]+partv[m][t+96];
  }
  __syncthreads();

  if (t<96){
    #pragma unroll
    for(int m=0;m<4;m++){
      float val;
      if (t<64) val=fabsf(mrow[m][t]);
      else { int o2=t-64;
        float a=mrow[m][64+o2*3],b=mrow[m][64+o2*3+1],c=mrow[m][64+o2*3+2];
        val=sqrtf(a*a+b*b+c*c); }
      n0_[m][t]=val;
    }
  }
  __syncthreads();
  {
    const int m=t>>6;
    float mu=0.f,ss2=0.f;
    for(int i=0;i<96;i++){ float v=n0_[m][i]; mu+=v; ss2+=v*v; }
    mu*=(1.f/96.f);
    float var=fmaxf(ss2*(1.f/96.f)-mu*mu,0.f);
    float rstd=rsqrtf(var+1e-5f);
    if ((t&63)==0){ stat[m]=mu; stat[4+m]=rstd; }
  }
  __syncthreads();
  if (t<96){
    float gv = fg  ? ((const float*)ln_g)[t] : LD(ln_g,t,fg);
    float bv = fbb ? ((const float*)ln_b)[t] : LD(ln_b,t,fbb);
    #pragma unroll
    for(int m=0;m<4;m++)
      x1_[m][t]=(n0_[m][t]-stat[m])*stat[4+m]*gv+bv;
  }
  __syncthreads();
  if (t<96){
    float bb = fb1 ? ((const float*)b1)[t] : LD(b1,t,fb1);
    float a[4]={bb,bb,bb,bb};
    if (fastt){
      const float* w1=(const float*)W1;
      for(int i=0;i<96;i++){
        float w=w1[(u32)i*96+t];          // lane-coalesced over t
        #pragma unroll
        for(int m=0;m<4;m++) a[m]+=x1_[m][i]*w;
      }
    } else {
      for(int i=0;i<96;i++){
        float w=LD(W1,i*96+t,f1);
        #pragma unroll
        for(int m=0;m<4;m++) a[m]+=x1_[m][i]*w;
      }
    }
    #pragma unroll
    for(int m=0;m<4;m++) y1_[m][t]=a[m]/(1.f+__expf(-a[m]));      // silu
  }
  __syncthreads();
  if (t<96){
    float bb = fb2 ? ((const float*)b2)[t] : LD(b2,t,fb2);
    float a[4]={bb,bb,bb,bb};
    if (fastt){
      const float* w2=(const float*)W2;
      for(int i=0;i<96;i++){
        float w=w2[(u32)i*96+t];
        #pragma unroll
        for(int m=0;m<4;m++) a[m]+=y1_[m][i]*w;
      }
    } else {
      for(int i=0;i<96;i++){
        float w=LD(W2,i*96+t,f2);
        #pragma unroll
        for(int m=0;m<4;m++) a[m]+=y1_[m][i]*w;
      }
    }
    #pragma unroll
    for(int m=0;m<4;m++){
      float gg=a[m]/(1.f+__expf(-a[m]));
      fl_[m][t]=gg/(n0_[m][t]+1e-6f);
    }
  }
  __syncthreads();
  if (t<160){
    #pragma unroll
    for(int m=0;m<4;m++){
      float v;
      if (t<64) v=mrow[m][t]*fl_[m][t];
      else { int q=t-64; int o2=q/3; v=mrow[m][t]*fl_[m][64+o2]; }
      out[(u32)(g4+m)*160+t]=v;
    }
  }
}

// ---------------------------------------------------------------- launch
extern "C" void kernel_launch(void* const* d_in, const int* in_sizes, int n_in,
                              void* d_out, int out_size, void* d_ws, size_t ws_size,
                              hipStream_t stream)
{
  (void)in_sizes; (void)n_in;
  const void* X    = d_in[0];
  const void* rbf  = d_in[1];
  const void* rsh  = d_in[2];
  const void* ei   = d_in[3];
  const void* Wq_s = d_in[4];
  const void* Wq_v = d_in[5];
  const void* Wk_s = d_in[6];
  const void* Wk_v = d_in[7];
  const void* Wp_s = d_in[8];
  const void* Wp_v = d_in[9];
  const void* Wrbf = d_in[10];
  const void* Wv_s = d_in[11];
  const void* Wv_v = d_in[12];
  const void* Wm_s = d_in[13];
  const void* Wm_v = d_in[14];
  const void* ln_g = d_in[15];
  const void* ln_b = d_in[16];
  const void* W1   = d_in[17];
  const void* b1   = d_in[18];
  const void* W2   = d_in[19];
  const void* b2   = d_in[20];

  // ws layout (~44.5 MB) — identical footprint to the passing baseline
  char* w = (char*)d_ws;
  int* flags     = (int*)w;   w += 256;
  float* logits  = (float*)w; w += (size_t)NE*8*4;   // raw logits in elist order
  u32* imax      = (u32*)w;   w += (size_t)NN*8*4;   // CSR off/cur + Wfold/Vfold
  float* den     = (float*)w; w += (size_t)NN*8*4;   // CSR edge list
  char* uni = w;              w += (size_t)NN*1280*4;
  // uni phase 1: qtab | kbtab (4-head chunk tables, exact fit);
  // phase 2: pA | pB (overlay dead qtab)
  float* qtab  = (float*)uni;
  float* kbtab = (float*)(uni + (size_t)NN*640*4);
  float* pA    = (float*)uni;
  float* pB    = (float*)(uni + (size_t)NN*128*4);
  // imax sub-layout:
  //   [0, 32772)        csr counts -> csr_off (NN+1 u32)
  //   [49152, 81920)    csr_cur (NN u32)
  //   [98304, 229376)   Wfold (512*64 f32 = 128KB)
  //   [229376, 262144)  Vfold (8*32*32 f32 = 32KB)
  u32* csr_off = imax;
  u32* csr_cur = imax + 12288;
  float* Wfold = (float*)((char*)imax + 98304);
  float* Vfold = (float*)((char*)imax + 229376);
  u32* elist   = (u32*)den;            // NE u32 = 256KB exact
  // dotAA[NN][8] scratch lives in d_out (fully overwritten by k_nodeval)
  float* dotAA = (float*)d_out;
  size_t required = (size_t)(w - (char*)d_ws);

  if (ws_size < required){
    k_sentinel<<<(out_size+255)/256,256,0,stream>>>((float*)d_out, out_size);
    return;
  }

  k_detect<<<1,64,0,stream>>>(X,rbf,rsh,ei,Wq_s,Wq_v,Wk_s,Wk_v,Wp_s,Wp_v,
                              Wrbf,Wv_s,Wv_v,Wm_s,Wm_v,ln_g,ln_b,W1,b1,W2,b2,flags);
  // weight folding + CSR build
  k_fold<<<160,256,0,stream>>>(Wv_s,Wv_v,Wm_s,Wm_v,flags,Wfold,Vfold);
  hipMemsetAsync(imax, 0, (size_t)NN*4, stream);                 // counts = 0
  k_count<<<NE/256,256,0,stream>>>(ei,flags,imax);
  k_scan<<<1,256,0,stream>>>(imax,csr_off,csr_cur);
  k_fill<<<NE/256,256,0,stream>>>(ei,flags,csr_cur,elist);
  // 2 head-chunks (4 heads each): 4-node prep (head-major tables) then elist-grouped logits
  for (int c=0;c<2;c++){
    k_prep4<<<NN/4,384,0,stream>>>(X,Wq_s,Wq_v,Wk_s,Wk_v,flags,c*4,qtab,kbtab,dotAA);
    k_elog4<<<NE/8,512,0,stream>>>(ei,flags,qtab,kbtab,dotAA,elist,c*4,logits);
  }
  // phase 2: per-node p-halves (4 nodes/block, overlay dead tables), then fused softmax+gather+tail
  k_pprep<<<NN/4,256,0,stream>>>(X,Wp_s,Wp_v,flags,pA,pB);
  k_nodeval<<<NN/4,256,0,stream>>>(logits,pA,pB,csr_off,elist,ei,rbf,rsh,Wrbf,
                                   Wfold,Vfold,ln_g,ln_b,W1,b1,W2,b2,flags,(float*)d_out);
}

// Round 17
// 401.668 us; speedup vs baseline: 1.1665x; 1.0011x over previous
//
#include <hip/hip_runtime.h>

typedef unsigned short u16;
typedef unsigned int u32;

#define NN 8192
#define NE 65536
#define INV160 0.07905694150420949f   // 1/sqrt(160)

__device__ __forceinline__ float BF(u16 u){ return __uint_as_float(((u32)u)<<16); }
// dual-dtype load: f=1 -> f32, f=0 -> bf16
__device__ __forceinline__ float LD(const void* p, u32 i, int f){
  return f ? ((const float*)p)[i] : BF(((const u16*)p)[i]);
}
// dual int load: f64=1 -> int64, else int32
__device__ __forceinline__ int LDI(const void* p, u32 i, int f64){
  return f64 ? (int)((const long long*)p)[i] : ((const int*)p)[i];
}

// ---------------------------------------------------------------- per-buffer dtype detect
__global__ void k_detect(
    const void* b0, const void* b1, const void* b2, const void* b3,
    const void* b4, const void* b5, const void* b6, const void* b7,
    const void* b8, const void* b9, const void* b10, const void* b11,
    const void* b12, const void* b13, const void* b14, const void* b15,
    const void* b16, const void* b17, const void* b18, const void* b19,
    const void* b20, int* flags)
{
  const void* bufs[21] = {b0,b1,b2,b3,b4,b5,b6,b7,b8,b9,b10,
                          b11,b12,b13,b14,b15,b16,b17,b18,b19,b20};
  int i = threadIdx.x;
  if (i >= 21) return;
  const u32* w = (const u32*)bufs[i];
  if (i == 3){
    int allz = 1;
    for (int k=0;k<32;k++) if (w[2*k+1] != 0u) allz = 0;
    flags[3] = allz;             // 1 = int64
  } else {
    int cnt = 0;
    for (int k=0;k<40;k++){
      u32 lo = w[k] & 0xFFFFu;
      u32 e = (lo>>7)&0xFFu;
      if (e>=123u && e<=131u) cnt++;
    }
    flags[i] = (cnt>=20) ? 0 : 1;  // 0=bf16, 1=f32
  }
}

__global__ void k_sentinel(float* __restrict__ out, int n){
  int i = blockIdx.x*256+threadIdx.x;
  if (i<n) out[i] = 12345.0f;
}

// ---------------------------------------------------------------- per-node prep for one head-chunk (4 heads), 4 nodes/block
// qtab/kbtab per node 640 floats, HEAD-MAJOR: [local head][160] = [0..64) scalar d, [64..160) 3*j+c
// dotAA[n][8] (in d_out scratch): q.kA per head
__global__ __launch_bounds__(384) void k_prep4(
    const void* __restrict__ X, const void* __restrict__ Wq_s,
    const void* __restrict__ Wq_v, const void* __restrict__ Wk_s,
    const void* __restrict__ Wk_v, const int* __restrict__ flags,
    int hc0, float* __restrict__ qtab, float* __restrict__ kbtab,
    float* __restrict__ dotAA)
{
  __shared__ float xr[4][160];
  __shared__ float dsum[4][4];   // [node][local head]
  const int fX=flags[0], fqs=flags[4], fqv=flags[5], fks=flags[6], fkv=flags[7];
  const int fall = fqs & fqv & fks & fkv;
  const int t=threadIdx.x; const int n0=blockIdx.x*4;
  for(int u=t;u<640;u+=384){ int m=u/160,k=u-m*160; xr[m][k]=LD(X,(u32)(n0+m)*160+k,fX); }
  if (t<16) dsum[t>>2][t&3]=0.f;
  __syncthreads();
  if (t<256){
    // scalar outputs: local head lh=t>>6, dim d=t&63; o = hc0*64 + t
    const int lh=t>>6, d=t&63;
    const int o=hc0*64+t;
    float q[4]={0,0,0,0}, ka[4]={0,0,0,0}, kb[4]={0,0,0,0};
    if (fall){
      const float* wqs=(const float*)Wq_s;
      const float* wks=(const float*)Wk_s;
      for(int i=0;i<64;i++){
        float wq=wqs[(u32)i*512+o], wa=wks[(u32)i*512+o], wb=wks[(u32)(64+i)*512+o];
        #pragma unroll
        for(int m=0;m<4;m++){ float s=xr[m][i]; q[m]+=s*wq; ka[m]+=s*wa; kb[m]+=s*wb; }
      }
    } else {
      for(int i=0;i<64;i++){
        float wq=LD(Wq_s,(u32)i*512+o,fqs);
        float wa=LD(Wk_s,(u32)i*512+o,fks);
        float wb=LD(Wk_s,(u32)(64+i)*512+o,fks);
        #pragma unroll
        for(int m=0;m<4;m++){ float s=xr[m][i]; q[m]+=s*wq; ka[m]+=s*wa; kb[m]+=s*wb; }
      }
    }
    #pragma unroll
    for(int m=0;m<4;m++){
      float qs = q[m]*0.125f;                    // 1/sqrt(64)
      float kas= ka[m]*0.08838834764831845f;     // 1/sqrt(128)
      float kbs= kb[m]*0.08838834764831845f;
      u32 base=(u32)(n0+m)*640 + lh*160 + d;     // head-major
      qtab [base]=qs;
      kbtab[base]=kbs;
      float dd=qs*kas;
      for(int s2=1;s2<64;s2<<=1) dd+=__shfl_xor(dd,s2,64);
      if(d==0) atomicAdd(&dsum[m][lh],dd);
    }
  } else {
    // vector outputs: ol in [0,128), local head lh=ol>>5, j=ol&31; ov = hc0*32 + ol
    const int ol=t-256;
    const int lh=ol>>5, jj=ol&31;
    const int o=hc0*32+ol;
    float q[4][3]={}, ka[4][3]={}, kb[4][3]={};
    if (fall){
      const float* wqv=(const float*)Wq_v;
      const float* wkv=(const float*)Wk_v;
      for(int j=0;j<32;j++){
        float wq=wqv[(u32)j*256+o], wa=wkv[(u32)j*256+o], wb=wkv[(u32)(32+j)*256+o];
        #pragma unroll
        for(int m=0;m<4;m++){
          #pragma unroll
          for(int c=0;c<3;c++){
            float x=xr[m][64+j*3+c];
            q[m][c]+=x*wq; ka[m][c]+=x*wa; kb[m][c]+=x*wb;
          }
        }
      }
    } else {
      for(int j=0;j<32;j++){
        float wq=LD(Wq_v,(u32)j*256+o,fqv);
        float wa=LD(Wk_v,(u32)j*256+o,fkv);
        float wb=LD(Wk_v,(u32)(32+j)*256+o,fkv);
        #pragma unroll
        for(int m=0;m<4;m++){
          #pragma unroll
          for(int c=0;c<3;c++){
            float x=xr[m][64+j*3+c];
            q[m][c]+=x*wq; ka[m][c]+=x*wa; kb[m][c]+=x*wb;
          }
        }
      }
    }
    const float sq=0.17677669529663687f;   // 1/sqrt(32)
    const float sk=0.125f;                 // 1/sqrt(64)
    #pragma unroll
    for(int m=0;m<4;m++){
      float dd=0.f;
      u32 base=(u32)(n0+m)*640 + lh*160 + 64 + (u32)jj*3;   // head-major
      #pragma unroll
      for(int c=0;c<3;c++){
        float qs=q[m][c]*sq, kas=ka[m][c]*sk, kbs=kb[m][c]*sk;
        qtab[base+c]=qs; kbtab[base+c]=kbs;
        dd+=qs*kas;
      }
      for(int s2=1;s2<32;s2<<=1) dd+=__shfl_xor(dd,s2,64);
      if((t&31)==0) atomicAdd(&dsum[m][lh],dd);
    }
  }
  __syncthreads();
  if (t<16){ int m=t>>2, hh=t&3; dotAA[(u32)(n0+m)*8+hc0+hh]=dsum[m][hh]; }
}

// ---------------------------------------------------------------- per-edge logits for one 4-head chunk
// 8 edges/block via elist, 1 wave/edge; head-major tables: 16 lanes per head,
// 40 contiguous float4 per head, single-accumulator 4-level reduce.
// LOGITS ARE WRITTEN IN ELIST (POSITION) ORDER: logits[p*8+h], p = slot in elist.
__global__ __launch_bounds__(512) void k_elog4(
    const void* __restrict__ ei, const int* __restrict__ flags,
    const float* __restrict__ qtab, const float* __restrict__ kbtab,
    const float* __restrict__ dotAA, const u32* __restrict__ elist,
    int hc0, float* __restrict__ logits)
{
  const int f64=flags[3];
  const int t=threadIdx.x;
  const u32 pp=(u32)blockIdx.x*8+(t>>6);
  const int e=(int)elist[pp], l=t&63;
  const int src=LDI(ei,(u32)e,f64);
  const int dst=LDI(ei,(u32)NE+e,f64);
  const float4* q4=(const float4*)qtab + (u32)src*160;
  const float4* b4=(const float4*)kbtab + (u32)dst*160;
  const int hg=l>>4, lg=l&15;
  const int base4=hg*40;
  float acc;
  {
    float4 a=q4[base4+lg], b=b4[base4+lg];
    acc=a.x*b.x+a.y*b.y+a.z*b.z+a.w*b.w;
  }
  {
    float4 a=q4[base4+16+lg], b=b4[base4+16+lg];
    acc+=a.x*b.x+a.y*b.y+a.z*b.z+a.w*b.w;
  }
  if (lg<8){
    float4 a=q4[base4+32+lg], b=b4[base4+32+lg];
    acc+=a.x*b.x+a.y*b.y+a.z*b.z+a.w*b.w;
  }
  #pragma unroll
  for(int m=1;m<16;m<<=1) acc+=__shfl_xor(acc,m,64);
  if (lg==0)
    logits[pp*8+hc0+hg]=(dotAA[(u32)src*8+hc0+hg]+acc)*INV160;
}

// ---------------------------------------------------------------- weight folding: (Wv,Wm) -> Wfold, Vfold
__global__ __launch_bounds__(256) void k_fold(
    const void* __restrict__ Wv_s, const void* __restrict__ Wv_v,
    const void* __restrict__ Wm_s, const void* __restrict__ Wm_v,
    const int* __restrict__ flags,
    float* __restrict__ Wfold, float* __restrict__ Vfold)
{
  const int fvs=flags[11], fvv=flags[12], fms=flags[13], fmv=flags[14];
  const int b=blockIdx.x, t=threadIdx.x;
  if (b<128){
    int idx=b*256+t;            // [0,32768)
    int i=idx>>6, o=idx&63;
    int h=i>>6, iin=i&63;
    float a=0.f;
    for(int d=0;d<64;d++)
      a += LD(Wv_s,(u32)iin*512 + h*64 + d, fvs) * LD(Wm_s,(u32)(h*64+d)*64 + o, fms);
    Wfold[idx]=a*0.0055242717280199026f;   // 0.125 * 1/sqrt(512)
  } else {
    int idx=(b-128)*256+t;      // [0,8192)
    int h=idx>>10, r=idx&1023, j2=r>>5, o2=r&31;
    float a=0.f;
    for(int dl=0;dl<32;dl++){
      int i2=h*32+dl;
      a += (LD(Wv_v,(u32)j2*256+i2,fvv)+LD(Wv_v,(u32)(32+j2)*256+i2,fvv))
           *LD(Wm_v,(u32)i2*32+o2,fmv);
    }
    Vfold[idx]=a*0.0078125f;               // 0.125 * 0.0625  (idx = h*1024 + j2*32 + o2)
  }
}

// ---------------------------------------------------------------- per-node pA/pB halves of the p-linear, 4 nodes/block
__global__ __launch_bounds__(256) void k_pprep(
    const void* __restrict__ X, const void* __restrict__ Wp_s,
    const void* __restrict__ Wp_v, const int* __restrict__ flags,
    float* __restrict__ pA, float* __restrict__ pB)
{
  __shared__ float xr[4][160];
  const int fX=flags[0], fps=flags[8], fpv=flags[9];
  const int t=threadIdx.x, n0=blockIdx.x*4;
  for(int u=t;u<640;u+=256){ int m=u/160,k=u-m*160; xr[m][k]=LD(X,(u32)(n0+m)*160+k,fX); }
  __syncthreads();
  if (t<64){
    const int j=t&31, half=t>>5;
    float a[4]={0.f,0.f,0.f,0.f};
    if (fps){
      const float* wp=(const float*)Wp_s;
      for(int i=0;i<64;i++){
        float w=wp[(u32)(half*64+i)*32+j];
        #pragma unroll
        for(int m=0;m<4;m++) a[m]+=xr[m][i]*w;
      }
    } else {
      for(int i=0;i<64;i++){
        float w=LD(Wp_s,(u32)(half*64+i)*32+j,fps);
        #pragma unroll
        for(int m=0;m<4;m++) a[m]+=xr[m][i]*w;
      }
    }
    float* d_ = half? pB:pA;
    #pragma unroll
    for(int m=0;m<4;m++) d_[(u32)(n0+m)*128+j]=a[m]*0.08838834764831845f;  // 1/sqrt(128)
  } else {
    const int idx=t-64;        // [0,192)
    const int half=idx/96;
    const int r=idx-half*96;   // [0,96)
    const int j=r/3, c=r-3*j;
    float a[4]={0.f,0.f,0.f,0.f};
    if (fpv){
      const float* wp=(const float*)Wp_v;
      for(int k=0;k<32;k++){
        float w=wp[(u32)(half*32+k)*32+j];
        #pragma unroll
        for(int m=0;m<4;m++) a[m]+=xr[m][64+k*3+c]*w;
      }
    } else {
      for(int k=0;k<32;k++){
        float w=LD(Wp_v,(u32)(half*32+k)*32+j,fpv);
        #pragma unroll
        for(int m=0;m<4;m++) a[m]+=xr[m][64+k*3+c]*w;
      }
    }
    float* d_ = half? pB:pA;
    #pragma unroll
    for(int m=0;m<4;m++) d_[(u32)(n0+m)*128+32+j*3+c]=a[m]*0.125f;         // 1/sqrt(64)
  }
}

// ---------------------------------------------------------------- CSR build (lives in dead imax/den buffers)
__global__ __launch_bounds__(256) void k_count(
    const void* __restrict__ ei, const int* __restrict__ flags,
    u32* __restrict__ cnt)
{
  int e = blockIdx.x*256 + threadIdx.x;
  int dst = LDI(ei,(u32)NE+e,flags[3]);
  atomicAdd(&cnt[dst],1u);
}
// single block: exclusive scan of 8192 counts -> offsets (+copy for cursor)
__global__ __launch_bounds__(256) void k_scan(
    u32* __restrict__ cnt, u32* __restrict__ off, u32* __restrict__ cur)
{
  __shared__ u32 s[NN];
  __shared__ u32 tsum[256];
  const int t=threadIdx.x;
  for(int u=t;u<NN;u+=256) s[u]=cnt[u];
  __syncthreads();
  const u32 base=(u32)t*32;
  u32 sum=0;
  for(int k=0;k<32;k++) sum+=s[base+k];
  tsum[t]=sum;
  __syncthreads();
  if(t==0){
    u32 run=0;
    for(int i=0;i<256;i++){ u32 v=tsum[i]; tsum[i]=run; run+=v; }
  }
  __syncthreads();
  u32 run=tsum[t];
  for(int k=0;k<32;k++){
    u32 v=s[base+k];
    off[base+k]=run; cur[base+k]=run;
    run+=v;
  }
  if(t==255) off[NN]=run;   // = NE
}
__global__ __launch_bounds__(256) void k_fill(
    const void* __restrict__ ei, const int* __restrict__ flags,
    u32* __restrict__ cur, u32* __restrict__ elist)
{
  int e = blockIdx.x*256 + threadIdx.x;
  int dst = LDI(ei,(u32)NE+e,flags[3]);
  u32 p = atomicAdd(&cur[dst],1u);
  elist[p] = (u32)e;
}

// ---------------------------------------------------------------- per-node: fused softmax + edge-u + gather + folded tail, 4 NODES/BLOCK
// logits position-indexed (elist order); LDS <32KB via double overlay (tail scalars live in dead ag)
__global__ __launch_bounds__(256) void k_nodeval(
    const float* __restrict__ logits, const float* __restrict__ pA,
    const float* __restrict__ pBt,
    const u32* __restrict__ off, const u32* __restrict__ elist,
    const void* __restrict__ ei, const void* __restrict__ rbf,
    const void* __restrict__ rsh, const void* __restrict__ Wrbf,
    const float* __restrict__ Wfold, const float* __restrict__ Vfold,
    const void* __restrict__ ln_g, const void* __restrict__ ln_b,
    const void* __restrict__ W1, const void* __restrict__ b1,
    const void* __restrict__ W2, const void* __restrict__ b2,
    const int* __restrict__ flags, float* __restrict__ out)
{
  __shared__ float ag[4][1288];    // 20.6 KB; edge->fold accumulators, then tail scalars
  __shared__ float smemf[2816];    // 11 KB overlay region
  // edge-phase aliases (2816 floats exactly)
  float* wrb = smemf;                                  // [1024]
  float (*pB4)[128]  = (float(*)[128])(smemf+1024);    // [4][128] ends 1536
  float (*ubuf)[160] = (float(*)[160])(smemf+1536);    // [8][160] ends 2816
  // fold-phase aliases (1808 floats, reuse smemf after edge phase)
  float (*partf)[4][65] = (float(*)[4][65])smemf;      // [4][4][65] ends 1040
  float (*partv)[192] = (float(*)[192])(smemf+1040);   // ends 1808
  // tail scalars live in the (dead after fold) ag region
  float* agf = (float*)ag;
  float (*mrow)[160]  = (float(*)[160])(agf);          // [4][160] ends 640
  float (*n0_)[96]    = (float(*)[96])(agf+640);       // ends 1024
  float (*x1_)[96]    = (float(*)[96])(agf+1024);      // ends 1408
  float (*y1_)[96]    = (float(*)[96])(agf+1408);      // ends 1792
  float (*fl_)[96]    = (float(*)[96])(agf+1792);      // ends 2176
  float* stat = agf+2176;                              // mu[4], rstd[4]

  const int frb=flags[1], frs=flags[2], f64=flags[3], fwr=flags[10];
  const int fg=flags[15], fbb=flags[16], f1=flags[17], fb1=flags[18];
  const int f2=flags[19], fb2=flags[20];
  const int fastg = frb & frs;
  const int fastt = f1 & f2;
  const int t=threadIdx.x; const int g4=blockIdx.x*4;
  for(int u=t;u<1024;u+=256) wrb[u]=LD(Wrbf,u,fwr);
  #pragma unroll
  for(int m=0;m<4;m++) if (t<128) pB4[m][t]=pBt[(u32)(g4+m)*128+t];
  __syncthreads();

  const int h=t>>5, j=t&31;

  // -------- edge phase: loop over the block's 4 nodes
  for (int m=0;m<4;m++){
    const int n=g4+m;
    const u32 o0=off[n], o1=off[n+1];
    // fused scatter-softmax stats per (n,h): coalesced position-indexed reads
    const u32 pidx=o0+j;
    const float lg = (pidx<o1) ? logits[pidx*8+h] : -3.4e38f;
    float mx=lg;
    for(u32 p=o0+32+j; p<o1; p+=32) mx=fmaxf(mx, logits[p*8+h]);
    #pragma unroll
    for(int s2=1;s2<32;s2<<=1) mx=fmaxf(mx, __shfl_xor(mx,s2,32));
    const float ex0 = (pidx<o1) ? __expf(lg-mx) : 0.f;
    float sm=ex0;
    for(u32 p=o0+32+j; p<o1; p+=32) sm+=__expf(logits[p*8+h]-mx);
    #pragma unroll
    for(int s2=1;s2<32;s2<<=1) sm+=__shfl_xor(sm,s2,32);
    const float winv=(sm>0.f)?1.f/sm:0.f;
    const float we = ex0*winv;     // attn weight for edge at position o0+j (this head)

    float a0=0.f,a1=0.f,a2=0.f,a3=0.f,a4=0.f;
    for (u32 base=o0; base<o1; base+=8){
      u32 rem=o1-base; int nb = rem<8u ? (int)rem : 8;
      if (h<nb){
        u32 e=elist[base+h];
        int src=LDI(ei,e,f64);
        const float* pa=pA+(u32)src*128;
        float ps  = pa[j]        + pB4[m][j];
        float pv0 = pa[32+j*3+0] + pB4[m][32+j*3+0];
        float pv1 = pa[32+j*3+1] + pB4[m][32+j*3+1];
        float pv2 = pa[32+j*3+2] + pB4[m][32+j*3+2];
        float scs=0.f, scv=0.f;
        float rs0,rs1,rs2,rs3;
        if (fastg){
          const float* rb=(const float*)rbf + (size_t)e*16;
          #pragma unroll
          for(int r=0;r<16;r++){
            float x=rb[r];
            scs+=x*wrb[r*64+j]; scv+=x*wrb[r*64+32+j];
          }
          const float* rs=(const float*)rsh + (size_t)e*128;
          rs0=rs[j]; rs1=rs[32+j*3+0]; rs2=rs[32+j*3+1]; rs3=rs[32+j*3+2];
        } else {
          for(int r=0;r<16;r++){
            float x=LD(rbf,(u32)e*16+r,frb);
            scs+=x*wrb[r*64+j]; scv+=x*wrb[r*64+32+j];
          }
          rs0=LD(rsh,(u32)e*128+j,frs);
          rs1=LD(rsh,(u32)e*128+32+j*3+0,frs);
          rs2=LD(rsh,(u32)e*128+32+j*3+1,frs);
          rs3=LD(rsh,(u32)e*128+32+j*3+2,frs);
        }
        float ss = rs0 * scs * ps;
        float v0 = rs1 * scv * pv0;
        float v1 = rs2 * scv * pv1;
        float v2 = rs3 * scv * pv2;
        ubuf[h][j]        = ss*ss;
        ubuf[h][32+j]     = (v0*v0+v1*v1+v2*v2)*0.57735026918962576f;
        ubuf[h][64+3*j+0] = ss*v0;
        ubuf[h][64+3*j+1] = ss*v1;
        ubuf[h][64+3*j+2] = ss*v2;
      }
      __syncthreads();
      const int off0=(int)(base-o0);
      for(int q=0;q<nb;q++){
        const int idx=off0+q;
        float w;
        if (idx<32) w=__shfl(we, idx, 32);
        else        w=__expf(logits[(base+q)*8+h]-mx)*winv;
        a0+=w*ubuf[q][j];        a1+=w*ubuf[q][32+j];
        a2+=w*ubuf[q][64+3*j+0]; a3+=w*ubuf[q][64+3*j+1]; a4+=w*ubuf[q][64+3*j+2];
      }
      __syncthreads();
    }
    ag[m][h*64+j]=a0; ag[m][h*64+32+j]=a1;
    ag[m][512+h*96+3*j+0]=a2; ag[m][512+h*96+3*j+1]=a3; ag[m][512+h*96+3*j+2]=a4;
  }
  __syncthreads();   // edge-phase smemf dead; fold overlay begins

  // -------- folded scalar path: thread (o4=t&15, pp=t>>4): m=pp&3, i-group gq=pp>>2
  {
    const int o4=t&15, pp=t>>4;
    const int m=pp&3, gq=pp>>2;
    const float4* Wf4=(const float4*)Wfold;
    float ax=0.f,ay=0.f,az=0.f,aw=0.f;
    const int i0=gq*128;
    for(int i=i0;i<i0+128;i++){
      float a=ag[m][i];
      float4 wv=Wf4[(u32)i*16+o4];
      ax+=a*wv.x; ay+=a*wv.y; az+=a*wv.z; aw+=a*wv.w;
    }
    partf[gq][m][o4*4+0]=ax; partf[gq][m][o4*4+1]=ay;
    partf[gq][m][o4*4+2]=az; partf[gq][m][o4*4+3]=aw;
  }
  // folded vector path: loads shared across the 4 nodes
  if (t<192){
    const int o2=t&31, c=(t>>5)%3, p=t/96;
    float a[4]={0.f,0.f,0.f,0.f};
    for(int hh=p*4;hh<p*4+4;hh++)
      for(int j2=0;j2<32;j2++){
        float v=Vfold[(u32)hh*1024+j2*32+o2];
        #pragma unroll
        for(int m=0;m<4;m++) a[m]+=ag[m][512+hh*96+j2*3+c]*v;
      }
    #pragma unroll
    for(int m=0;m<4;m++) partv[m][t]=a[m];
  }
  __syncthreads();   // all ag reads done; ag region now hosts tail scalars
  {
    const int o=t&63, m=t>>6;
    mrow[m][o]=partf[0][m][o]+partf[1][m][o]+partf[2][m][o]+partf[3][m][o];
  }
  if (t<96){
    #pragma unroll
    for(int m=0;m<4;m++)
      mrow[m][64+(t&31)*3+(t>>5)]=partv[m][t]+partv[m][t+96];
  }
  __syncthreads();

  if (t<96){
    #pragma unroll
    for(int m=0;m<4;m++){
      float val;
      if (t<64) val=fabsf(mrow[m][t]);
      else { int o2=t-64;
        float a=mrow[m][64+o2*3],b=mrow[m][64+o2*3+1],c=mrow[m][64+o2*3+2];
        val=sqrtf(a*a+b*b+c*c); }
      n0_[m][t]=val;
    }
  }
  __syncthreads();
  {
    const int m=t>>6;
    float mu=0.f,ss2=0.f;
    for(int i=0;i<96;i++){ float v=n0_[m][i]; mu+=v; ss2+=v*v; }
    mu*=(1.f/96.f);
    float var=fmaxf(ss2*(1.f/96.f)-mu*mu,0.f);
    float rstd=rsqrtf(var+1e-5f);
    if ((t&63)==0){ stat[m]=mu; stat[4+m]=rstd; }
  }
  __syncthreads();
  if (t<96){
    float gv = fg  ? ((const float*)ln_g)[t] : LD(ln_g,t,fg);
    float bv = fbb ? ((const float*)ln_b)[t] : LD(ln_b,t,fbb);
    #pragma unroll
    for(int m=0;m<4;m++)
      x1_[m][t]=(n0_[m][t]-stat[m])*stat[4+m]*gv+bv;
  }
  __syncthreads();
  if (t<96){
    float bb = fb1 ? ((const float*)b1)[t] : LD(b1,t,fb1);
    float a[4]={bb,bb,bb,bb};
    if (fastt){
      const float* w1=(const float*)W1;
      for(int i=0;i<96;i++){
        float w=w1[(u32)i*96+t];          // lane-coalesced over t
        #pragma unroll
        for(int m=0;m<4;m++) a[m]+=x1_[m][i]*w;
      }
    } else {
      for(int i=0;i<96;i++){
        float w=LD(W1,i*96+t,f1);
        #pragma unroll
        for(int m=0;m<4;m++) a[m]+=x1_[m][i]*w;
      }
    }
    #pragma unroll
    for(int m=0;m<4;m++) y1_[m][t]=a[m]/(1.f+__expf(-a[m]));      // silu
  }
  __syncthreads();
  if (t<96){
    float bb = fb2 ? ((const float*)b2)[t] : LD(b2,t,fb2);
    float a[4]={bb,bb,bb,bb};
    if (fastt){
      const float* w2=(const float*)W2;
      for(int i=0;i<96;i++){
        float w=w2[(u32)i*96+t];
        #pragma unroll
        for(int m=0;m<4;m++) a[m]+=y1_[m][i]*w;
      }
    } else {
      for(int i=0;i<96;i++){
        float w=LD(W2,i*96+t,f2);
        #pragma unroll
        for(int m=0;m<4;m++) a[m]+=y1_[m][i]*w;
      }
    }
    #pragma unroll
    for(int m=0;m<4;m++){
      float gg=a[m]/(1.f+__expf(-a[m]));
      fl_[m][t]=gg/(n0_[m][t]+1e-6f);
    }
  }
  __syncthreads();
  if (t<160){
    #pragma unroll
    for(int m=0;m<4;m++){
      float v;
      if (t<64) v=mrow[m][t]*fl_[m][t];
      else { int q=t-64; int o2=q/3; v=mrow[m][t]*fl_[m][64+o2]; }
      out[(u32)(g4+m)*160+t]=v;
    }
  }
}

// ---------------------------------------------------------------- launch
extern "C" void kernel_launch(void* const* d_in, const int* in_sizes, int n_in,
                              void* d_out, int out_size, void* d_ws, size_t ws_size,
                              hipStream_t stream)
{
  (void)in_sizes; (void)n_in;
  const void* X    = d_in[0];
  const void* rbf  = d_in[1];
  const void* rsh  = d_in[2];
  const void* ei   = d_in[3];
  const void* Wq_s = d_in[4];
  const void* Wq_v = d_in[5];
  const void* Wk_s = d_in[6];
  const void* Wk_v = d_in[7];
  const void* Wp_s = d_in[8];
  const void* Wp_v = d_in[9];
  const void* Wrbf = d_in[10];
  const void* Wv_s = d_in[11];
  const void* Wv_v = d_in[12];
  const void* Wm_s = d_in[13];
  const void* Wm_v = d_in[14];
  const void* ln_g = d_in[15];
  const void* ln_b = d_in[16];
  const void* W1   = d_in[17];
  const void* b1   = d_in[18];
  const void* W2   = d_in[19];
  const void* b2   = d_in[20];

  // ws layout (~44.5 MB) — identical footprint to the passing baseline
  char* w = (char*)d_ws;
  int* flags     = (int*)w;   w += 256;
  float* logits  = (float*)w; w += (size_t)NE*8*4;   // raw logits in elist order
  u32* imax      = (u32*)w;   w += (size_t)NN*8*4;   // CSR off/cur + Wfold/Vfold
  float* den     = (float*)w; w += (size_t)NN*8*4;   // CSR edge list
  char* uni = w;              w += (size_t)NN*1280*4;
  // uni phase 1: qtab | kbtab (4-head chunk tables, exact fit);
  // phase 2: pA | pB (overlay dead qtab)
  float* qtab  = (float*)uni;
  float* kbtab = (float*)(uni + (size_t)NN*640*4);
  float* pA    = (float*)uni;
  float* pB    = (float*)(uni + (size_t)NN*128*4);
  // imax sub-layout:
  //   [0, 32772)        csr counts -> csr_off (NN+1 u32)
  //   [49152, 81920)    csr_cur (NN u32)
  //   [98304, 229376)   Wfold (512*64 f32 = 128KB)
  //   [229376, 262144)  Vfold (8*32*32 f32 = 32KB)
  u32* csr_off = imax;
  u32* csr_cur = imax + 12288;
  float* Wfold = (float*)((char*)imax + 98304);
  float* Vfold = (float*)((char*)imax + 229376);
  u32* elist   = (u32*)den;            // NE u32 = 256KB exact
  // dotAA[NN][8] scratch lives in d_out (fully overwritten by k_nodeval)
  float* dotAA = (float*)d_out;
  size_t required = (size_t)(w - (char*)d_ws);

  if (ws_size < required){
    k_sentinel<<<(out_size+255)/256,256,0,stream>>>((float*)d_out, out_size);
    return;
  }

  k_detect<<<1,64,0,stream>>>(X,rbf,rsh,ei,Wq_s,Wq_v,Wk_s,Wk_v,Wp_s,Wp_v,
                              Wrbf,Wv_s,Wv_v,Wm_s,Wm_v,ln_g,ln_b,W1,b1,W2,b2,flags);
  // weight folding + CSR build
  k_fold<<<160,256,0,stream>>>(Wv_s,Wv_v,Wm_s,Wm_v,flags,Wfold,Vfold);
  hipMemsetAsync(imax, 0, (size_t)NN*4, stream);                 // counts = 0
  k_count<<<NE/256,256,0,stream>>>(ei,flags,imax);
  k_scan<<<1,256,0,stream>>>(imax,csr_off,csr_cur);
  k_fill<<<NE/256,256,0,stream>>>(ei,flags,csr_cur,elist);
  // 2 head-chunks (4 heads each): 4-node prep (head-major tables) then elist-grouped logits
  for (int c=0;c<2;c++){
    k_prep4<<<NN/4,384,0,stream>>>(X,Wq_s,Wq_v,Wk_s,Wk_v,flags,c*4,qtab,kbtab,dotAA);
    k_elog4<<<NE/8,512,0,stream>>>(ei,flags,qtab,kbtab,dotAA,elist,c*4,logits);
  }
  // phase 2: per-node p-halves (4 nodes/block, overlay dead tables), then fused softmax+gather+tail
  k_pprep<<<NN/4,256,0,stream>>>(X,Wp_s,Wp_v,flags,pA,pB);
  k_nodeval<<<NN/4,256,0,stream>>>(logits,pA,pB,csr_off,elist,ei,rbf,rsh,Wrbf,
                                   Wfold,Vfold,ln_g,ln_b,W1,b1,W2,b2,flags,(float*)d_out);
}